// Round 3
// baseline (437.073 us; speedup 1.0000x reference)
//
#include <hip/hip_runtime.h>
#include <hip/hip_bf16.h>

typedef __attribute__((ext_vector_type(8))) short short8;
typedef __attribute__((ext_vector_type(4))) short bfx4;
typedef __attribute__((ext_vector_type(4))) float floatx4;

#define SEQ     2048
#define DMODEL  768
#define DINNER  1536
#define DSTATE  128
#define NH      24
#define CONVDIM 1792
#define NPROJ   3352   // 2*DINNER + 2*DSTATE + NH
#define QCH     64     // SSD chunk length
#define NCH     (SEQ / QCH)   // 32 chunks

__device__ inline float bf2f(short s) {
    return __uint_as_float(((unsigned)(unsigned short)s) << 16);
}
__device__ inline short f2bf(float f) {
    __hip_bfloat16 h = __float2bfloat16(f);
    return *reinterpret_cast<short*>(&h);
}
__device__ inline void gl_lds16(const void* g, void* l) {
    __builtin_amdgcn_global_load_lds((const __attribute__((address_space(1))) unsigned int*)g,
                                     (__attribute__((address_space(3))) unsigned int*)l, 16, 0, 0);
}

// ---------------------------------------------------------------- converts (float4)
__global__ __launch_bounds__(256) void cvt_kernel(const float* __restrict__ src,
                                                  __hip_bfloat16* __restrict__ dst, int n4) {
    int i = blockIdx.x * 256 + threadIdx.x;
    if (i >= n4) return;
    float4 v = *(const float4*)(src + (size_t)i * 4);
    bfx4 o = { f2bf(v.x), f2bf(v.y), f2bf(v.z), f2bf(v.w) };
    *(bfx4*)((short*)dst + (size_t)i * 4) = o;
}

// ---------------------------------------------------------------- GEMM 256x256, BK=64, 8 waves, m201 4-phase schedule
// Phase s = C-quadrant (Ah,Bh)=(s>>1,s&1): reads ONLY A-half Ah + B-half Bh (12 ds_read_b128),
// stages ONE half-tile (2 gl_lds), 16 MFMA. 2 LDS dbufs (128 KB); staging lead 4-6 phases.
// Wait ledger (2 loads per half-tile, per-wave): s=0 vmcnt(8) [needs Ah0/Bh0 of kt; outstanding
// Ah1/Bh1(kt), Ah0/Bh0(kt+1)], s=1 vmcnt(6) [needs Bh1(kt)], s=2/3 none (older data already waited).
// Stage slots: s0->Ah1(kt+1), s1->Bh1(kt+1), s2->Ah0(kt+2), s3->Bh0(kt+2); target region's last
// reader always finished before this phase's entry barrier (per-quadrant read pattern).
// LDS unit = 8KB, 128 rows x 32 K, packed row-pair XOR slot map (0 conflicts measured R0-R2).
// mode 1: out_proj atomicAdd (dir1 flips C rows). mode 2: in_proj routing epilogue.
#define GPHASE(AH, BH, WAITC, STAGEC) do {                                      \
    WAITC;                                                                       \
    __builtin_amdgcn_s_barrier();                                                \
    __builtin_amdgcn_sched_barrier(0);                                           \
    STAGEC;                                                                      \
    const short* Au0 = &As[dbuf][AH][0][0];                                      \
    const short* Au1 = &As[dbuf][AH][1][0];                                      \
    const short* Bu0 = &Bs[dbuf][BH][0][0];                                      \
    const short* Bu1 = &Bs[dbuf][BH][1][0];                                      \
    short8 af0[4], af1[4], bq0[2], bq1[2];                                       \
    _Pragma("unroll")                                                            \
    for (int mi = 0; mi < 4; mi++) {                                             \
        af0[mi] = *(const short8*)&Au0[aRd[mi]];                                 \
        af1[mi] = *(const short8*)&Au1[aRd[mi]];                                 \
    }                                                                            \
    _Pragma("unroll")                                                            \
    for (int ni = 0; ni < 2; ni++) {                                             \
        bq0[ni] = *(const short8*)&Bu0[bRd[ni]];                                 \
        bq1[ni] = *(const short8*)&Bu1[bRd[ni]];                                 \
    }                                                                            \
    __builtin_amdgcn_s_setprio(1);                                               \
    _Pragma("unroll")                                                            \
    for (int mi = 0; mi < 4; mi++)                                               \
    _Pragma("unroll")                                                            \
    for (int ni = 0; ni < 2; ni++) {                                             \
        acc[(((AH)*2+(BH))*4+mi)*2+ni] = __builtin_amdgcn_mfma_f32_16x16x32_bf16(\
            af0[mi], bq0[ni], acc[(((AH)*2+(BH))*4+mi)*2+ni], 0, 0, 0);          \
        acc[(((AH)*2+(BH))*4+mi)*2+ni] = __builtin_amdgcn_mfma_f32_16x16x32_bf16(\
            af1[mi], bq1[ni], acc[(((AH)*2+(BH))*4+mi)*2+ni], 0, 0, 0);          \
    }                                                                            \
    __builtin_amdgcn_s_setprio(0);                                               \
} while (0)

__global__ __launch_bounds__(512, 2) void gemm256(const __hip_bfloat16* __restrict__ Abase, size_t aStride,
                                                  const __hip_bfloat16* __restrict__ Bbase, size_t bStride,
                                                  float* __restrict__ C,
                                                  __hip_bfloat16* __restrict__ Zb,
                                                  __hip_bfloat16* __restrict__ Xb,
                                                  float* __restrict__ DT,
                                                  float* __restrict__ LA,
                                                  const float* __restrict__ dtbias,
                                                  const float* __restrict__ Alog,
                                                  int M, int N, int K, int zdiv, int mode, int flipA) {
    __shared__ short As[2][2][2][4096];   // [dbuf][half][kchunk-unit][8KB unit]  = 64 KB
    __shared__ short Bs[2][2][2][4096];   // 128 KB total
    int tid = threadIdx.x;
    int w = tid >> 6, lane = tid & 63;
    int q = lane >> 4, mm = lane & 15;
    int wm = w >> 2, wn = w & 3;          // wave grid 2M x 4N within each 128x128 quadrant
    int m0 = blockIdx.x * 256, n0 = blockIdx.y * 256;
    int z = blockIdx.z;
    int dir = z / zdiv, ks = z - dir * zdiv;
    int kl = K / zdiv, kbeg = ks * kl;
    int nkt = kl / 64;                    // 64-wide K-tiles
    const short* Ag = (const short*)Abase + (size_t)dir * aStride;
    const short* Bg = (const short*)Bbase + (size_t)dir * bStride;
    int fA = flipA && dir;

    // staging thread map: unit = 128 rows x 32 K; 8 waves x 8 lines, 1 load/thread/unit
    int ln   = w * 8 + (lane >> 3);       // line 0..63
    int sl   = lane & 7;                  // 16B slot
    int cc   = sl ^ (ln & 7);             // XOR slot map
    int lrow = (cc < 4) ? ln : ln + 64;   // row within 128-row unit
    int chk  = (cc < 4) ? cc : (cc ^ 4);  // K-chunk (8 elems)
    int wbase = w * 512;                  // wave-uniform LDS window (1KB, HW adds lane*16B)
    size_t aoff[2], boff[2];
#pragma unroll
    for (int h = 0; h < 2; h++) {
        int ar = m0 + h * 128 + lrow;
        if (fA) { int bb = ar >> 11, tt = ar & 2047; ar = (bb << 11) + (2047 - tt); }
        aoff[h] = (size_t)ar * K + chk * 8;
        int br = n0 + h * 128 + lrow; if (br > N - 1) br = N - 1;   // dup rows; cols skipped on store
        boff[h] = (size_t)br * K + chk * 8;
    }

    // fragment read offsets (verified layout: line*64 + slot*8; slot XORs row-hi via bit2)
    int slotA = (q ^ (mm & 7) ^ (wm << 2)) * 8;
    int slotB = (q ^ (mm & 7) ^ ((wn >> 1) << 2)) * 8;
    int aRd[4], bRd[2];
#pragma unroll
    for (int mi = 0; mi < 4; mi++) aRd[mi] = (mi * 16 + mm) * 64 + slotA;
#pragma unroll
    for (int ni = 0; ni < 2; ni++) bRd[ni] = ((wn & 1) * 32 + ni * 16 + mm) * 64 + slotB;

    floatx4 acc[32];
#pragma unroll
    for (int i = 0; i < 32; i++) acc[i] = (floatx4){0.f, 0.f, 0.f, 0.f};

    auto stageA = [&](int kt2, int h) {
        int d = kt2 & 1;
        const short* s0 = Ag + aoff[h] + kbeg + kt2 * 64;
        gl_lds16(s0,      &As[d][h][0][wbase]);
        gl_lds16(s0 + 32, &As[d][h][1][wbase]);
    };
    auto stageB = [&](int kt2, int h) {
        int d = kt2 & 1;
        const short* s0 = Bg + boff[h] + kbeg + kt2 * 64;
        gl_lds16(s0,      &Bs[d][h][0][wbase]);
        gl_lds16(s0 + 32, &Bs[d][h][1][wbase]);
    };

    // prologue (issue order = ledger order): Ah0[0],Bh0[0],Ah1[0],Bh1[0],Ah0[1],Bh0[1]
    stageA(0, 0); stageB(0, 0);
    stageA(0, 1); stageB(0, 1);
    if (nkt > 1) { stageA(1, 0); stageB(1, 0); }

    for (int kt = 0; kt < nkt; kt++) {
        int dbuf = kt & 1;
        GPHASE(0, 0,
            { if (kt + 1 < nkt) asm volatile("s_waitcnt vmcnt(8)" ::: "memory");
              else              asm volatile("s_waitcnt vmcnt(4)" ::: "memory"); },
            { if (kt + 1 < nkt) stageA(kt + 1, 1); });
        GPHASE(0, 1,
            { if (kt + 1 < nkt) asm volatile("s_waitcnt vmcnt(6)" ::: "memory");
              else              asm volatile("s_waitcnt vmcnt(0)" ::: "memory"); },
            { if (kt + 1 < nkt) stageB(kt + 1, 1); });
        GPHASE(1, 0, { }, { if (kt + 2 < nkt) stageA(kt + 2, 0); });
        GPHASE(1, 1, { }, { if (kt + 2 < nkt) stageB(kt + 2, 0); });
    }

    // ---- epilogue
    __hip_bfloat16* Zb2 = Zb + (size_t)dir * 4096 * DINNER;
    __hip_bfloat16* Xb2 = Xb + (size_t)dir * 4096 * CONVDIM;
    float* DT2 = DT + (size_t)dir * 4096 * NH;
    float* LA2 = LA + (size_t)dir * 4096 * NH;
    const float* dtb2 = dtbias ? dtbias + dir * NH : nullptr;
    const float* Al2  = Alog ? Alog + dir * NH : nullptr;

#pragma unroll
    for (int Ah = 0; Ah < 2; Ah++) {
#pragma unroll
        for (int Bh = 0; Bh < 2; Bh++) {
#pragma unroll
            for (int mi = 0; mi < 4; mi++) {
#pragma unroll
                for (int ni = 0; ni < 2; ni++) {
                    int col = n0 + Bh * 128 + wn * 32 + ni * 16 + mm;
                    if (col >= N) continue;
#pragma unroll
                    for (int r = 0; r < 4; r++) {
                        int rr = m0 + Ah * 128 + wm * 64 + mi * 16 + q * 4 + r;
                        float v = acc[((Ah * 2 + Bh) * 4 + mi) * 2 + ni][r];
                        if (mode == 1) {
                            int orow = rr;
                            if (dir) { int b = rr >> 11, t = rr & 2047; orow = (b << 11) + (2047 - t); }
                            atomicAdd(&C[(size_t)orow * N + col], v);
                        } else {
                            if (col < DINNER) {
                                Zb2[(size_t)rr * DINNER + col] = __float2bfloat16(v);
                            } else if (col < DINNER + CONVDIM) {
                                Xb2[(size_t)rr * CONVDIM + (col - DINNER)] = __float2bfloat16(v);
                            } else {
                                int hh = col - (DINNER + CONVDIM);
                                float raw = v + dtb2[hh];
                                float dtv = (raw > 20.f) ? raw : log1pf(__expf(raw));
                                float Av  = -__expf(Al2[hh]);
                                DT2[(size_t)rr * NH + hh] = dtv;
                                LA2[(size_t)rr * NH + hh] = dtv * Av;
                            }
                        }
                    }
                }
            }
        }
    }
}

// ---------------------------------------------------------------- conv (depthwise K=4) + silu
__global__ __launch_bounds__(256) void conv_kernel(const __hip_bfloat16* __restrict__ Xb,
                                                   const float* __restrict__ conv_w,
                                                   const float* __restrict__ conv_b,
                                                   __hip_bfloat16* __restrict__ xh,
                                                   __hip_bfloat16* __restrict__ Bm,
                                                   __hip_bfloat16* __restrict__ Cm) {
    int db  = blockIdx.x >> 7;
    int dir = db >> 1;
    int t0  = (blockIdx.x & 127) * 16;
    int c8  = threadIdx.x * 8;
    if (c8 >= CONVDIM) return;

    float wk[4][8], bs[8];
#pragma unroll
    for (int j = 0; j < 8; j++) {
        bs[j] = conv_b[dir * CONVDIM + c8 + j];
#pragma unroll
        for (int k = 0; k < 4; k++) wk[k][j] = conv_w[((size_t)dir * CONVDIM + c8 + j) * 4 + k];
    }

    const short* xrow = (const short*)Xb + (size_t)db * SEQ * CONVDIM + c8;
    short8 win[4];
    const short8 zer = {0, 0, 0, 0, 0, 0, 0, 0};
#pragma unroll
    for (int k = 0; k < 3; k++) {
        int ts = t0 - 3 + k;
        win[k] = (ts >= 0) ? *(const short8*)(xrow + (size_t)ts * CONVDIM) : zer;
    }

    for (int tt = 0; tt < 16; tt++) {
        int t = t0 + tt;
        win[3] = *(const short8*)(xrow + (size_t)t * CONVDIM);
        short8 outv;
#pragma unroll
        for (int j = 0; j < 8; j++) {
            float acc = bs[j];
#pragma unroll
            for (int k = 0; k < 4; k++) acc += wk[k][j] * bf2f(win[k][j]);
            float sv = acc / (1.f + __expf(-acc));
            outv[j] = f2bf(sv);
        }
        if (c8 < DINNER)
            *(short8*)((short*)xh + (size_t)(db * SEQ + t) * DINNER + c8) = outv;
        else if (c8 < DINNER + DSTATE)
            *(short8*)((short*)Bm + (size_t)(db * SEQ + t) * DSTATE + (c8 - DINNER)) = outv;
        else
            *(short8*)((short*)Cm + (size_t)(db * SEQ + t) * DSTATE + (c8 - DINNER - DSTATE)) = outv;
        win[0] = win[1]; win[1] = win[2]; win[2] = win[3];
    }
}

// ---------------------------------------------------------------- SSD pass 1
__global__ __launch_bounds__(256) void ssd1_kernel(const __hip_bfloat16* __restrict__ XH,
                                                   const __hip_bfloat16* __restrict__ BMh,
                                                   const float* __restrict__ DT,
                                                   const float* __restrict__ LA,
                                                   short* __restrict__ SS,
                                                   float* __restrict__ CUM) {
    int blk = blockIdx.x;
    int ck = blk & 31;
    int dbh = blk >> 5;
    int hh = dbh % NH, db = dbh / NH;
    int base_row = db * SEQ + ck * QCH;

    __shared__ float cum_s[QCH], dt_s[QCH];
    __shared__ short Xt[64][72];
    __shared__ short Bt[128][72];

    int tid = threadIdx.x;
    int lane = tid & 63, w = tid >> 6;
    int q = lane >> 4, mm = lane & 15;

    if (tid < QCH) {
        float la  = LA[(size_t)(base_row + tid) * NH + hh];
        float dtv = DT[(size_t)(base_row + tid) * NH + hh];
        float cs = la;
#pragma unroll
        for (int d = 1; d < 64; d <<= 1) {
            float u = __shfl_up(cs, d);
            if (tid >= d) cs += u;
        }
        cum_s[tid] = cs;
        dt_s[tid] = dtv;
        CUM[(size_t)dbh * SEQ + ck * QCH + tid] = cs;
    }
    __syncthreads();
    float cumL = cum_s[QCH - 1];

    {
        int s2 = (tid & 31) * 2, pb = tid >> 5;
        float f0 = dt_s[s2]     * __expf(cumL - cum_s[s2]);
        float f1 = dt_s[s2 + 1] * __expf(cumL - cum_s[s2 + 1]);
        const short* r0 = (const short*)XH + (size_t)(base_row + s2) * DINNER + hh * 64 + pb * 8;
        const short* r1 = r0 + DINNER;
        short8 x0 = *(const short8*)r0;
        short8 x1 = *(const short8*)r1;
#pragma unroll
        for (int j = 0; j < 8; j++) {
            unsigned lo = (unsigned short)f2bf(f0 * bf2f(x0[j]));
            unsigned hi = (unsigned short)f2bf(f1 * bf2f(x1[j]));
            *(unsigned*)&Xt[pb * 8 + j][s2] = lo | (hi << 16);
        }
    }
    {
        int s2 = (tid & 31) * 2, nb = tid >> 5;
        const short* r0 = (const short*)BMh + (size_t)(base_row + s2) * DSTATE + nb * 16;
        const short* r1 = r0 + DSTATE;
        short8 b0a = *(const short8*)r0,  b0b = *(const short8*)(r0 + 8);
        short8 b1a = *(const short8*)r1,  b1b = *(const short8*)(r1 + 8);
#pragma unroll
        for (int j = 0; j < 8; j++) {
            *(unsigned*)&Bt[nb * 16 + j][s2] =
                (unsigned)(unsigned short)b0a[j] | ((unsigned)(unsigned short)b1a[j] << 16);
            *(unsigned*)&Bt[nb * 16 + 8 + j][s2] =
                (unsigned)(unsigned short)b0b[j] | ((unsigned)(unsigned short)b1b[j] << 16);
        }
    }
    __syncthreads();

    floatx4 acc[8];
#pragma unroll
    for (int i = 0; i < 8; i++) acc[i] = (floatx4){0.f, 0.f, 0.f, 0.f};
#pragma unroll
    for (int kk = 0; kk < 2; kk++) {
        short8 a = *(const short8*)&Xt[w * 16 + mm][kk * 32 + q * 8];
#pragma unroll
        for (int cb = 0; cb < 8; cb++) {
            short8 b = *(const short8*)&Bt[cb * 16 + mm][kk * 32 + q * 8];
            acc[cb] = __builtin_amdgcn_mfma_f32_16x16x32_bf16(a, b, acc[cb], 0, 0, 0);
        }
    }
    short* Sp = SS + (size_t)blk * 8192;
#pragma unroll
    for (int cb = 0; cb < 8; cb++)
#pragma unroll
        for (int r = 0; r < 4; r++)
            Sp[(w * 16 + q * 4 + r) * DSTATE + cb * 16 + mm] = f2bf(acc[cb][r]);
}

// ---------------------------------------------------------------- SSD pass 2: inter-chunk scan
__global__ __launch_bounds__(256) void ssd2_kernel(const short* __restrict__ SS,
                                                   const float* __restrict__ CUM,
                                                   short* __restrict__ Hprev) {
    int blk = blockIdx.x;
    int dbh = blk >> 2, part = blk & 3;
    int off = part * 2048 + threadIdx.x * 8;
    size_t base = (size_t)dbh * NCH * 8192 + off;
    float h[8];
#pragma unroll
    for (int j = 0; j < 8; j++) h[j] = 0.f;
    for (int c = 0; c < NCH; c++) {
        float W = __expf(CUM[(size_t)dbh * SEQ + c * QCH + QCH - 1]);
        size_t p = base + (size_t)c * 8192;
        short8 s = *(const short8*)(SS + p);
        short8 o;
#pragma unroll
        for (int j = 0; j < 8; j++) o[j] = f2bf(h[j]);
        *(short8*)(Hprev + p) = o;
#pragma unroll
        for (int j = 0; j < 8; j++) h[j] = fmaf(h[j], W, bf2f(s[j]));
    }
}

// ---------------------------------------------------------------- SSD pass 3
__global__ __launch_bounds__(256) void ssd3_kernel(const __hip_bfloat16* __restrict__ XH,
                                                   const __hip_bfloat16* __restrict__ BMh,
                                                   const __hip_bfloat16* __restrict__ CMh,
                                                   const float* __restrict__ DT,
                                                   const float* __restrict__ CUM,
                                                   const short* __restrict__ Hprev,
                                                   __hip_bfloat16* __restrict__ Yb) {
    int blk = blockIdx.x;
    int ck = blk & 31;
    int dbh = blk >> 5;
    int hh = dbh % NH, db = dbh / NH;
    int base_row = db * SEQ + ck * QCH;

    __shared__ float cum_s[QCH], dt_s[QCH];
    __shared__ short Ct[64][136];
    __shared__ short G[64][72];
    __shared__ short Xt[64][72];

    int tid = threadIdx.x;
    int lane = tid & 63, w = tid >> 6;
    int q = lane >> 4, mm = lane & 15;

    if (tid < QCH) {
        cum_s[tid] = CUM[(size_t)dbh * SEQ + ck * QCH + tid];
        dt_s[tid]  = DT[(size_t)(base_row + tid) * NH + hh];
    }

    const short* Cg = (const short*)CMh + (size_t)base_row * DSTATE;
    const short* Bg = (const short*)BMh + (size_t)base_row * DSTATE;
    floatx4 P[4];
#pragma unroll
    for (int i = 0; i < 4; i++) P[i] = (floatx4){0.f, 0.f, 0.f, 0.f};
#pragma unroll
    for (int kk = 0; kk < 4; kk++) {
        short8 a = *(const short8*)(Cg + (size_t)(w * 16 + mm) * DSTATE + kk * 32 + q * 8);
#pragma unroll
        for (int cb = 0; cb < 4; cb++) {
            short8 b = *(const short8*)(Bg + (size_t)(cb * 16 + mm) * DSTATE + kk * 32 + q * 8);
            P[cb] = __builtin_amdgcn_mfma_f32_16x16x32_bf16(a, b, P[cb], 0, 0, 0);
        }
    }
    __syncthreads();

    {
        int t = tid & 63, nb4 = tid >> 6;
        float wt = __expf(cum_s[t]);
        const short* src = Cg + (size_t)t * DSTATE + nb4 * 32;
#pragma unroll
        for (int u = 0; u < 2; u++) {
            short8 v = *(const short8*)(src + u * 16);
            short8 v2 = *(const short8*)(src + u * 16 + 8);
#pragma unroll
            for (int j = 0; j < 4; j++) {
                unsigned lo = (unsigned short)f2bf(wt * bf2f(v[2 * j]));
                unsigned hi = (unsigned short)f2bf(wt * bf2f(v[2 * j + 1]));
                *(unsigned*)&Ct[t][nb4 * 32 + u * 16 + 2 * j] = lo | (hi << 16);
                lo = (unsigned short)f2bf(wt * bf2f(v2[2 * j]));
                hi = (unsigned short)f2bf(wt * bf2f(v2[2 * j + 1]));
                *(unsigned*)&Ct[t][nb4 * 32 + u * 16 + 8 + 2 * j] = lo | (hi << 16);
            }
        }
    }
    {
        int s2 = (tid & 31) * 2, pb = tid >> 5;
        const short* r0 = (const short*)XH + (size_t)(base_row + s2) * DINNER + hh * 64 + pb * 8;
        const short* r1 = r0 + DINNER;
        short8 x0 = *(const short8*)r0;
        short8 x1 = *(const short8*)r1;
#pragma unroll
        for (int j = 0; j < 8; j++) {
            *(unsigned*)&Xt[pb * 8 + j][s2] =
                (unsigned)(unsigned short)x0[j] | ((unsigned)(unsigned short)x1[j] << 16);
        }
    }
#pragma unroll
    for (int cb = 0; cb < 4; cb++) {
#pragma unroll
        for (int r = 0; r < 4; r++) {
            int t = w * 16 + q * 4 + r;
            int s = cb * 16 + mm;
            float g = (s <= t) ? P[cb][r] * __expf(cum_s[t] - cum_s[s]) * dt_s[s] : 0.f;
            G[t][s] = f2bf(g);
        }
    }
    __syncthreads();

    floatx4 Y[4];
#pragma unroll
    for (int i = 0; i < 4; i++) Y[i] = (floatx4){0.f, 0.f, 0.f, 0.f};
#pragma unroll
    for (int kk = 0; kk < 2; kk++) {
        short8 a = *(const short8*)&G[w * 16 + mm][kk * 32 + q * 8];
#pragma unroll
        for (int cb = 0; cb < 4; cb++) {
            short8 b = *(const short8*)&Xt[cb * 16 + mm][kk * 32 + q * 8];
            Y[cb] = __builtin_amdgcn_mfma_f32_16x16x32_bf16(a, b, Y[cb], 0, 0, 0);
        }
    }
    const short* Hc = Hprev + (size_t)blk * 8192;
#pragma unroll
    for (int kk = 0; kk < 4; kk++) {
        short8 a = *(const short8*)&Ct[w * 16 + mm][kk * 32 + q * 8];
#pragma unroll
        for (int cb = 0; cb < 4; cb++) {
            short8 b = *(const short8*)(Hc + (size_t)(cb * 16 + mm) * DSTATE + kk * 32 + q * 8);
            Y[cb] = __builtin_amdgcn_mfma_f32_16x16x32_bf16(a, b, Y[cb], 0, 0, 0);
        }
    }
#pragma unroll
    for (int cb = 0; cb < 4; cb++)
#pragma unroll
        for (int r = 0; r < 4; r++)
            Yb[(size_t)(base_row + w * 16 + q * 4 + r) * DINNER + hh * 64 + cb * 16 + mm] =
                __float2bfloat16(Y[cb][r]);
}

// ---------------------------------------------------------------- gating + RMSNorm (192 thr x 8 ch)
__global__ __launch_bounds__(192) void gate_kernel(const __hip_bfloat16* __restrict__ Yb,
                                                   const __hip_bfloat16* __restrict__ xh,
                                                   const __hip_bfloat16* __restrict__ Zb,
                                                   const float* __restrict__ Dp,
                                                   const float* __restrict__ norm_w,
                                                   __hip_bfloat16* __restrict__ A2) {
    int row = blockIdx.x;
    int dir = row >> 12;
    int c8 = threadIdx.x * 8;
    int hd = c8 >> 6;
    const short* yr = (const short*)Yb + (size_t)row * DINNER + c8;
    const short* xr = (const short*)xh + (size_t)row * DINNER + c8;
    const short* zr = (const short*)Zb + (size_t)row * DINNER + c8;

    short8 y8 = *(const short8*)yr;
    short8 x8 = *(const short8*)xr;
    short8 z8 = *(const short8*)zr;
    float Dv = Dp[dir * NH + hd];

    float vals[8];
    float ss = 0.f;
#pragma unroll
    for (int j = 0; j < 8; j++) {
        float v = bf2f(y8[j]) + Dv * bf2f(x8[j]);
        float z = bf2f(z8[j]);
        v *= z / (1.f + __expf(-z));
        vals[j] = v;
        ss += v * v;
    }
#pragma unroll
    for (int off = 32; off; off >>= 1) ss += __shfl_down(ss, off);
    __shared__ float ls[3];
    if ((threadIdx.x & 63) == 0) ls[threadIdx.x >> 6] = ss;
    __syncthreads();
    float tot = ls[0] + ls[1] + ls[2];
    float scale = rsqrtf(tot / (float)DINNER + 1e-5f);

    const float* nw = norm_w + dir * DINNER + c8;
    short8 o;
#pragma unroll
    for (int j = 0; j < 8; j++) o[j] = f2bf(vals[j] * scale * nw[j]);
    *(short8*)((short*)A2 + (size_t)row * DINNER + c8) = o;
}

// ---------------------------------------------------------------- launch
extern "C" void kernel_launch(void* const* d_in, const int* in_sizes, int n_in,
                              void* d_out, int out_size, void* d_ws, size_t ws_size,
                              hipStream_t stream) {
    const float* x        = (const float*)d_in[0];
    const float* in_w     = (const float*)d_in[1];
    const float* conv_w   = (const float*)d_in[2];
    const float* conv_b   = (const float*)d_in[3];
    const float* dt_bias  = (const float*)d_in[4];
    const float* A_log    = (const float*)d_in[5];
    const float* Dp       = (const float*)d_in[6];
    const float* norm_w   = (const float*)d_in[7];
    const float* out_w    = (const float*)d_in[8];
    float* out = (float*)d_out;

    const size_t szW2 = (size_t)2 * DMODEL * DINNER * 2;
    const size_t szZ  = (size_t)8192 * DINNER * 2;
    const size_t szXH = (size_t)8192 * DINNER * 2;
    const size_t szBM = (size_t)8192 * DSTATE * 2;
    const size_t szCM = szBM;
    const size_t szDT = (size_t)8192 * NH * 4;
    const size_t szLA = szDT;
    const size_t szA1 = (size_t)4096 * DMODEL * 2;     // unflipped, shared by both dirs
    const size_t szW1 = (size_t)2 * NPROJ * DMODEL * 2;
    const size_t szXB = (size_t)8192 * CONVDIM * 2;
    const size_t szYb = (size_t)8192 * DINNER * 2;
    const size_t szSS = (size_t)96 * NCH * 8192 * 2;
    const size_t szRa = szA1 + szW1 + szXB;
    size_t szR = szRa;
    if (szR < szYb) szR = szYb;
    if (szR < szSS) szR = szSS;
    const size_t szHp = szSS;
    const size_t szCU = (size_t)96 * SEQ * 4;

    char* ws = (char*)d_ws;
    size_t off = 0;
    auto alloc = [&](size_t bytes) { char* p = ws + off; off += (bytes + 255) & ~(size_t)255; return p; };

    __hip_bfloat16* W2 = (__hip_bfloat16*)alloc(szW2);
    __hip_bfloat16* Z  = (__hip_bfloat16*)alloc(szZ);
    __hip_bfloat16* XH = (__hip_bfloat16*)alloc(szXH);
    __hip_bfloat16* BM = (__hip_bfloat16*)alloc(szBM);
    __hip_bfloat16* CM = (__hip_bfloat16*)alloc(szCM);
    float* DT = (float*)alloc(szDT);
    float* LA = (float*)alloc(szLA);
    char*  R  = (char*)alloc(szR);
    __hip_bfloat16* A1  = (__hip_bfloat16*)R;
    __hip_bfloat16* W1  = (__hip_bfloat16*)(R + szA1);
    __hip_bfloat16* XBC = (__hip_bfloat16*)(R + szA1 + szW1);
    short* SS = (short*)R;
    __hip_bfloat16* Yb = (__hip_bfloat16*)R;

    short* Hp = (short*)alloc(szHp);
    float* CU = (float*)alloc(szCU);
    if (off > ws_size) return;   // clean fail instead of OOB crash

    // 1. converts (float4): weights + x (A1 rows = b*SEQ+t, unflipped)
    int n1 = 2 * NPROJ * DMODEL / 4;
    cvt_kernel<<<(n1 + 255) / 256, 256, 0, stream>>>(in_w, W1, n1);
    int n2 = 2 * DMODEL * DINNER / 4;
    cvt_kernel<<<(n2 + 255) / 256, 256, 0, stream>>>(out_w, W2, n2);
    int n3 = 4096 * DMODEL / 4;
    cvt_kernel<<<(n3 + 255) / 256, 256, 0, stream>>>(x, A1, n3);

    // 2. in_proj GEMM: 256^2 4-phase schedule, z = dir, dir1 flips A rows in-gather
    {
        dim3 grid(4096 / 256, (NPROJ + 255) / 256, 2);
        gemm256<<<grid, 512, 0, stream>>>(A1, 0,
                                          W1, (size_t)NPROJ * DMODEL,
                                          nullptr, Z, XBC, DT, LA, dt_bias, A_log,
                                          4096, NPROJ, DMODEL, 1, 2, 1);
    }

    // 3. conv + silu
    conv_kernel<<<4 * 128, 256, 0, stream>>>(XBC, conv_w, conv_b, XH, BM, CM);

    // 4. SSD chunked scan (3-pass)
    ssd1_kernel<<<4 * NH * NCH, 256, 0, stream>>>(XH, BM, DT, LA, SS, CU);
    ssd2_kernel<<<4 * NH * 4, 256, 0, stream>>>(SS, CU, Hp);
    ssd3_kernel<<<4 * NH * NCH, 256, 0, stream>>>(XH, BM, CM, DT, CU, Hp, Yb);

    // 5. gating + RMSNorm (A2 == Z, in-place)
    gate_kernel<<<2 * 4096, 192, 0, stream>>>(Yb, XH, Z, Dp, norm_w, Z);

    // 6. out_proj: zero-init, 256^2 4-phase kernel, z = dir*2 + kslice, atomic adds, dir1 flips C rows
    hipMemsetAsync(out, 0, (size_t)4096 * DMODEL * 4, stream);
    {
        dim3 grid(4096 / 256, DMODEL / 256, 4);
        gemm256<<<grid, 512, 0, stream>>>(Z, (size_t)4096 * DINNER,
                                          W2, (size_t)DMODEL * DINNER,
                                          out, nullptr, nullptr, nullptr, nullptr, nullptr, nullptr,
                                          4096, DMODEL, DINNER, 2, 1, 0);
    }
}

// Round 4
// 384.826 us; speedup vs baseline: 1.1358x; 1.1358x over previous
//
#include <hip/hip_runtime.h>
#include <hip/hip_bf16.h>

typedef __attribute__((ext_vector_type(8))) short short8;
typedef __attribute__((ext_vector_type(4))) short bfx4;
typedef __attribute__((ext_vector_type(4))) float floatx4;

#define SEQ     2048
#define DMODEL  768
#define DINNER  1536
#define DSTATE  128
#define NH      24
#define CONVDIM 1792
#define NPROJ   3352   // 2*DINNER + 2*DSTATE + NH
#define QCH     64     // SSD chunk length
#define NCH     (SEQ / QCH)   // 32 chunks

__device__ inline float bf2f(short s) {
    return __uint_as_float(((unsigned)(unsigned short)s) << 16);
}
__device__ inline short f2bf(float f) {
    __hip_bfloat16 h = __float2bfloat16(f);
    return *reinterpret_cast<short*>(&h);
}
__device__ inline void gl_lds16(const void* g, void* l) {
    __builtin_amdgcn_global_load_lds((const __attribute__((address_space(1))) unsigned int*)g,
                                     (__attribute__((address_space(3))) unsigned int*)l, 16, 0, 0);
}

// ---------------------------------------------------------------- fused converts (float4), 3 segments
__global__ __launch_bounds__(256) void cvt3_kernel(const float* __restrict__ s1, __hip_bfloat16* __restrict__ d1, int n1,
                                                   const float* __restrict__ s2, __hip_bfloat16* __restrict__ d2, int n2,
                                                   const float* __restrict__ s3, __hip_bfloat16* __restrict__ d3, int n3) {
    int i = blockIdx.x * 256 + threadIdx.x;
    const float* src; __hip_bfloat16* dst; int idx;
    if (i < n1)                { src = s1; dst = d1; idx = i; }
    else if (i < n1 + n2)      { src = s2; dst = d2; idx = i - n1; }
    else if (i < n1 + n2 + n3) { src = s3; dst = d3; idx = i - n1 - n2; }
    else return;
    float4 v = *(const float4*)(src + (size_t)idx * 4);
    bfx4 o = { f2bf(v.x), f2bf(v.y), f2bf(v.z), f2bf(v.w) };
    *(bfx4*)((short*)dst + (size_t)idx * 4) = o;
}

// ---------------------------------------------------------------- GEMM 64x128 tile, BK=32, 4 waves, double-buffered
// SMALLER tile / BIGGER grid: the counters say latency/occupancy-bound (all pipes <17%,
// occupancy 24%); 24KB LDS + ~64 VGPR allow 6 blocks/CU (24 waves) vs R0's effective ~2.
// Schedule is byte-identical to the measured-104us R0 kernel (__syncthreads, stage(it+1)
// inside loop, 2 bufs). LDS: packed row-pair XOR slot map (0 conflicts measured R0-R3);
// A unit = 32 lines x 128B (rows l & l+32), B unit = 64 lines x 128B (rows l & l+64).
// blockIdx.z: dir = z/zdiv, kslice = z%zdiv. flipA: dir1 reads A rows flipped (shared A1).
// mode 1: out_proj atomic add (row flipped when dir==1); C pre-zeroed.
// mode 2: in_proj routing epilogue (per-dir output offsets).
__global__ __launch_bounds__(256) void gemm_bt(const __hip_bfloat16* __restrict__ Abase, size_t aStride,
                                               const __hip_bfloat16* __restrict__ Bbase, size_t bStride,
                                               float* __restrict__ C,
                                               __hip_bfloat16* __restrict__ Zb,
                                               __hip_bfloat16* __restrict__ Xb,
                                               float* __restrict__ DT,
                                               float* __restrict__ LA,
                                               const float* __restrict__ dtbias,
                                               const float* __restrict__ Alog,
                                               int M, int N, int K, int zdiv, int mode, int flipA) {
    __shared__ short As[2][32 * 64];   // 4 KB per buf: 32 lines x 128 B (rows l & l+32 packed)
    __shared__ short Bs[2][64 * 64];   // 8 KB per buf: 64 lines x 128 B (rows l & l+64 packed)
    int tid = threadIdx.x;
    int w = tid >> 6, lane = tid & 63;
    int q = lane >> 4, mm = lane & 15;
    int wm = w >> 1, wn = w & 1;       // wave tile 32x64 within 64x128 block tile
    int m0 = blockIdx.x * 64, n0 = blockIdx.y * 128;
    int z = blockIdx.z;
    int dir = z / zdiv, ks = z - dir * zdiv;
    int kl = K / zdiv;
    int kbeg = ks * kl;
    const short* Ag = (const short*)Abase + (size_t)dir * aStride;
    const short* Bg = (const short*)Bbase + (size_t)dir * bStride;
    int fA = flipA && dir;

    // A staging: 4 waves x 8 lines = 32 lines, 1 load/thread
    size_t aoff; int aldso;
    {
        int ln = w * 8 + (lane >> 3);    // line 0..31
        int s  = lane & 7;               // slot within line
        int c  = s ^ (ln & 7);
        int row = (c < 4) ? ln : ln + 32;
        int ch  = (c < 4) ? c : (c ^ 4);
        int ar = m0 + row;
        if (fA) { int bb = ar >> 11, tt = ar & 2047; ar = (bb << 11) + (2047 - tt); }
        aoff = (size_t)ar * K + ch * 8;
        aldso = w * 1024;                // bytes
    }
    // B staging: 8 windows (w*2+j) x 8 lines = 64 lines, 2 loads/thread
    size_t boff[2];
    int bldso[2];
#pragma unroll
    for (int j = 0; j < 2; j++) {
        int widx = w * 2 + j;            // 0..7
        int ln = widx * 8 + (lane >> 3); // line 0..63
        int s  = lane & 7;
        int c  = s ^ (ln & 7);
        int row = (c < 4) ? ln : ln + 64;
        int ch  = (c < 4) ? c : (c ^ 4);
        int br = n0 + row; if (br > N - 1) br = N - 1;   // dup rows; cols skipped on store
        boff[j] = (size_t)br * K + ch * 8;
        bldso[j] = widx * 1024;          // bytes
    }

    floatx4 acc[8];
#pragma unroll
    for (int i = 0; i < 8; i++) acc[i] = (floatx4){0.f, 0.f, 0.f, 0.f};

    int niter = kl / 32;
    auto stage = [&](int buf, int k0) {
        gl_lds16(Ag + aoff + kbeg + k0, (char*)&As[buf][0] + aldso);
        gl_lds16(Bg + boff[0] + kbeg + k0, (char*)&Bs[buf][0] + bldso[0]);
        gl_lds16(Bg + boff[1] + kbeg + k0, (char*)&Bs[buf][0] + bldso[1]);
    };
    stage(0, 0);
    int slotA = (q ^ (mm & 7) ^ (wm << 2)) * 8;   // elements
    int slotB = (q ^ (mm & 7) ^ (wn << 2)) * 8;
    for (int it = 0; it < niter; it++) {
        __syncthreads();                           // buf[it&1] staged; prior reads done
        if (it + 1 < niter) stage((it + 1) & 1, (it + 1) * 32);
        const short* Ab = &As[it & 1][0];
        const short* Bb = &Bs[it & 1][0];
        short8 af[2], bfr[4];
#pragma unroll
        for (int mb = 0; mb < 2; mb++)
            af[mb] = *(const short8*)&Ab[(mb * 16 + mm) * 64 + slotA];
#pragma unroll
        for (int nb = 0; nb < 4; nb++)
            bfr[nb] = *(const short8*)&Bb[(nb * 16 + mm) * 64 + slotB];
#pragma unroll
        for (int mb = 0; mb < 2; mb++)
#pragma unroll
            for (int nb = 0; nb < 4; nb++)
                acc[mb * 4 + nb] = __builtin_amdgcn_mfma_f32_16x16x32_bf16(af[mb], bfr[nb], acc[mb * 4 + nb], 0, 0, 0);
    }

    __hip_bfloat16* Zb2 = Zb + (size_t)dir * 4096 * DINNER;
    __hip_bfloat16* Xb2 = Xb + (size_t)dir * 4096 * CONVDIM;
    float* DT2 = DT + (size_t)dir * 4096 * NH;
    float* LA2 = LA + (size_t)dir * 4096 * NH;
    const float* dtb2 = dtbias ? dtbias + dir * NH : nullptr;
    const float* Al2  = Alog ? Alog + dir * NH : nullptr;

#pragma unroll
    for (int mb = 0; mb < 2; mb++) {
#pragma unroll
        for (int nb = 0; nb < 4; nb++) {
            int col = n0 + wn * 64 + nb * 16 + mm;
            if (col >= N) continue;
#pragma unroll
            for (int r = 0; r < 4; r++) {
                int rr = m0 + wm * 32 + mb * 16 + q * 4 + r;
                float v = acc[mb * 4 + nb][r];
                if (mode == 1) {
                    int orow = rr;
                    if (dir) { int b = rr >> 11, t = rr & 2047; orow = (b << 11) + (2047 - t); }
                    atomicAdd(&C[(size_t)orow * N + col], v);
                } else {
                    if (col < DINNER) {
                        Zb2[(size_t)rr * DINNER + col] = __float2bfloat16(v);
                    } else if (col < DINNER + CONVDIM) {
                        Xb2[(size_t)rr * CONVDIM + (col - DINNER)] = __float2bfloat16(v);
                    } else {
                        int hh = col - (DINNER + CONVDIM);
                        float raw = v + dtb2[hh];
                        float dtv = (raw > 20.f) ? raw : log1pf(__expf(raw));
                        float Av  = -__expf(Al2[hh]);
                        DT2[(size_t)rr * NH + hh] = dtv;
                        LA2[(size_t)rr * NH + hh] = dtv * Av;
                    }
                }
            }
        }
    }
}

// ---------------------------------------------------------------- conv (depthwise K=4) + silu
__global__ __launch_bounds__(256) void conv_kernel(const __hip_bfloat16* __restrict__ Xb,
                                                   const float* __restrict__ conv_w,
                                                   const float* __restrict__ conv_b,
                                                   __hip_bfloat16* __restrict__ xh,
                                                   __hip_bfloat16* __restrict__ Bm,
                                                   __hip_bfloat16* __restrict__ Cm) {
    int db  = blockIdx.x >> 7;
    int dir = db >> 1;
    int t0  = (blockIdx.x & 127) * 16;
    int c8  = threadIdx.x * 8;
    if (c8 >= CONVDIM) return;

    float wk[4][8], bs[8];
#pragma unroll
    for (int j = 0; j < 8; j++) {
        bs[j] = conv_b[dir * CONVDIM + c8 + j];
#pragma unroll
        for (int k = 0; k < 4; k++) wk[k][j] = conv_w[((size_t)dir * CONVDIM + c8 + j) * 4 + k];
    }

    const short* xrow = (const short*)Xb + (size_t)db * SEQ * CONVDIM + c8;
    short8 win[4];
    const short8 zer = {0, 0, 0, 0, 0, 0, 0, 0};
#pragma unroll
    for (int k = 0; k < 3; k++) {
        int ts = t0 - 3 + k;
        win[k] = (ts >= 0) ? *(const short8*)(xrow + (size_t)ts * CONVDIM) : zer;
    }

    for (int tt = 0; tt < 16; tt++) {
        int t = t0 + tt;
        win[3] = *(const short8*)(xrow + (size_t)t * CONVDIM);
        short8 outv;
#pragma unroll
        for (int j = 0; j < 8; j++) {
            float acc = bs[j];
#pragma unroll
            for (int k = 0; k < 4; k++) acc += wk[k][j] * bf2f(win[k][j]);
            float sv = acc / (1.f + __expf(-acc));
            outv[j] = f2bf(sv);
        }
        if (c8 < DINNER)
            *(short8*)((short*)xh + (size_t)(db * SEQ + t) * DINNER + c8) = outv;
        else if (c8 < DINNER + DSTATE)
            *(short8*)((short*)Bm + (size_t)(db * SEQ + t) * DSTATE + (c8 - DINNER)) = outv;
        else
            *(short8*)((short*)Cm + (size_t)(db * SEQ + t) * DSTATE + (c8 - DINNER - DSTATE)) = outv;
        win[0] = win[1]; win[1] = win[2]; win[2] = win[3];
    }
}

// ---------------------------------------------------------------- SSD pass 1
__global__ __launch_bounds__(256) void ssd1_kernel(const __hip_bfloat16* __restrict__ XH,
                                                   const __hip_bfloat16* __restrict__ BMh,
                                                   const float* __restrict__ DT,
                                                   const float* __restrict__ LA,
                                                   short* __restrict__ SS,
                                                   float* __restrict__ CUM) {
    int blk = blockIdx.x;
    int ck = blk & 31;
    int dbh = blk >> 5;
    int hh = dbh % NH, db = dbh / NH;
    int base_row = db * SEQ + ck * QCH;

    __shared__ float cum_s[QCH], dt_s[QCH];
    __shared__ short Xt[64][72];
    __shared__ short Bt[128][72];

    int tid = threadIdx.x;
    int lane = tid & 63, w = tid >> 6;
    int q = lane >> 4, mm = lane & 15;

    if (tid < QCH) {
        float la  = LA[(size_t)(base_row + tid) * NH + hh];
        float dtv = DT[(size_t)(base_row + tid) * NH + hh];
        float cs = la;
#pragma unroll
        for (int d = 1; d < 64; d <<= 1) {
            float u = __shfl_up(cs, d);
            if (tid >= d) cs += u;
        }
        cum_s[tid] = cs;
        dt_s[tid] = dtv;
        CUM[(size_t)dbh * SEQ + ck * QCH + tid] = cs;
    }
    __syncthreads();
    float cumL = cum_s[QCH - 1];

    {
        int s2 = (tid & 31) * 2, pb = tid >> 5;
        float f0 = dt_s[s2]     * __expf(cumL - cum_s[s2]);
        float f1 = dt_s[s2 + 1] * __expf(cumL - cum_s[s2 + 1]);
        const short* r0 = (const short*)XH + (size_t)(base_row + s2) * DINNER + hh * 64 + pb * 8;
        const short* r1 = r0 + DINNER;
        short8 x0 = *(const short8*)r0;
        short8 x1 = *(const short8*)r1;
#pragma unroll
        for (int j = 0; j < 8; j++) {
            unsigned lo = (unsigned short)f2bf(f0 * bf2f(x0[j]));
            unsigned hi = (unsigned short)f2bf(f1 * bf2f(x1[j]));
            *(unsigned*)&Xt[pb * 8 + j][s2] = lo | (hi << 16);
        }
    }
    {
        int s2 = (tid & 31) * 2, nb = tid >> 5;
        const short* r0 = (const short*)BMh + (size_t)(base_row + s2) * DSTATE + nb * 16;
        const short* r1 = r0 + DSTATE;
        short8 b0a = *(const short8*)r0,  b0b = *(const short8*)(r0 + 8);
        short8 b1a = *(const short8*)r1,  b1b = *(const short8*)(r1 + 8);
#pragma unroll
        for (int j = 0; j < 8; j++) {
            *(unsigned*)&Bt[nb * 16 + j][s2] =
                (unsigned)(unsigned short)b0a[j] | ((unsigned)(unsigned short)b1a[j] << 16);
            *(unsigned*)&Bt[nb * 16 + 8 + j][s2] =
                (unsigned)(unsigned short)b0b[j] | ((unsigned)(unsigned short)b1b[j] << 16);
        }
    }
    __syncthreads();

    floatx4 acc[8];
#pragma unroll
    for (int i = 0; i < 8; i++) acc[i] = (floatx4){0.f, 0.f, 0.f, 0.f};
#pragma unroll
    for (int kk = 0; kk < 2; kk++) {
        short8 a = *(const short8*)&Xt[w * 16 + mm][kk * 32 + q * 8];
#pragma unroll
        for (int cb = 0; cb < 8; cb++) {
            short8 b = *(const short8*)&Bt[cb * 16 + mm][kk * 32 + q * 8];
            acc[cb] = __builtin_amdgcn_mfma_f32_16x16x32_bf16(a, b, acc[cb], 0, 0, 0);
        }
    }
    short* Sp = SS + (size_t)blk * 8192;
#pragma unroll
    for (int cb = 0; cb < 8; cb++)
#pragma unroll
        for (int r = 0; r < 4; r++)
            Sp[(w * 16 + q * 4 + r) * DSTATE + cb * 16 + mm] = f2bf(acc[cb][r]);
}

// ---------------------------------------------------------------- SSD pass 2: inter-chunk scan
__global__ __launch_bounds__(256) void ssd2_kernel(const short* __restrict__ SS,
                                                   const float* __restrict__ CUM,
                                                   short* __restrict__ Hprev) {
    int blk = blockIdx.x;
    int dbh = blk >> 2, part = blk & 3;
    int off = part * 2048 + threadIdx.x * 8;
    size_t base = (size_t)dbh * NCH * 8192 + off;
    float h[8];
#pragma unroll
    for (int j = 0; j < 8; j++) h[j] = 0.f;
    for (int c = 0; c < NCH; c++) {
        float W = __expf(CUM[(size_t)dbh * SEQ + c * QCH + QCH - 1]);
        size_t p = base + (size_t)c * 8192;
        short8 s = *(const short8*)(SS + p);
        short8 o;
#pragma unroll
        for (int j = 0; j < 8; j++) o[j] = f2bf(h[j]);
        *(short8*)(Hprev + p) = o;
#pragma unroll
        for (int j = 0; j < 8; j++) h[j] = fmaf(h[j], W, bf2f(s[j]));
    }
}

// ---------------------------------------------------------------- SSD pass 3
__global__ __launch_bounds__(256) void ssd3_kernel(const __hip_bfloat16* __restrict__ XH,
                                                   const __hip_bfloat16* __restrict__ BMh,
                                                   const __hip_bfloat16* __restrict__ CMh,
                                                   const float* __restrict__ DT,
                                                   const float* __restrict__ CUM,
                                                   const short* __restrict__ Hprev,
                                                   __hip_bfloat16* __restrict__ Yb) {
    int blk = blockIdx.x;
    int ck = blk & 31;
    int dbh = blk >> 5;
    int hh = dbh % NH, db = dbh / NH;
    int base_row = db * SEQ + ck * QCH;

    __shared__ float cum_s[QCH], dt_s[QCH];
    __shared__ short Ct[64][136];
    __shared__ short G[64][72];
    __shared__ short Xt[64][72];

    int tid = threadIdx.x;
    int lane = tid & 63, w = tid >> 6;
    int q = lane >> 4, mm = lane & 15;

    if (tid < QCH) {
        cum_s[tid] = CUM[(size_t)dbh * SEQ + ck * QCH + tid];
        dt_s[tid]  = DT[(size_t)(base_row + tid) * NH + hh];
    }

    const short* Cg = (const short*)CMh + (size_t)base_row * DSTATE;
    const short* Bg = (const short*)BMh + (size_t)base_row * DSTATE;
    floatx4 P[4];
#pragma unroll
    for (int i = 0; i < 4; i++) P[i] = (floatx4){0.f, 0.f, 0.f, 0.f};
#pragma unroll
    for (int kk = 0; kk < 4; kk++) {
        short8 a = *(const short8*)(Cg + (size_t)(w * 16 + mm) * DSTATE + kk * 32 + q * 8);
#pragma unroll
        for (int cb = 0; cb < 4; cb++) {
            short8 b = *(const short8*)(Bg + (size_t)(cb * 16 + mm) * DSTATE + kk * 32 + q * 8);
            P[cb] = __builtin_amdgcn_mfma_f32_16x16x32_bf16(a, b, P[cb], 0, 0, 0);
        }
    }
    __syncthreads();

    {
        int t = tid & 63, nb4 = tid >> 6;
        float wt = __expf(cum_s[t]);
        const short* src = Cg + (size_t)t * DSTATE + nb4 * 32;
#pragma unroll
        for (int u = 0; u < 2; u++) {
            short8 v = *(const short8*)(src + u * 16);
            short8 v2 = *(const short8*)(src + u * 16 + 8);
#pragma unroll
            for (int j = 0; j < 4; j++) {
                unsigned lo = (unsigned short)f2bf(wt * bf2f(v[2 * j]));
                unsigned hi = (unsigned short)f2bf(wt * bf2f(v[2 * j + 1]));
                *(unsigned*)&Ct[t][nb4 * 32 + u * 16 + 2 * j] = lo | (hi << 16);
                lo = (unsigned short)f2bf(wt * bf2f(v2[2 * j]));
                hi = (unsigned short)f2bf(wt * bf2f(v2[2 * j + 1]));
                *(unsigned*)&Ct[t][nb4 * 32 + u * 16 + 8 + 2 * j] = lo | (hi << 16);
            }
        }
    }
    {
        int s2 = (tid & 31) * 2, pb = tid >> 5;
        const short* r0 = (const short*)XH + (size_t)(base_row + s2) * DINNER + hh * 64 + pb * 8;
        const short* r1 = r0 + DINNER;
        short8 x0 = *(const short8*)r0;
        short8 x1 = *(const short8*)r1;
#pragma unroll
        for (int j = 0; j < 8; j++) {
            *(unsigned*)&Xt[pb * 8 + j][s2] =
                (unsigned)(unsigned short)x0[j] | ((unsigned)(unsigned short)x1[j] << 16);
        }
    }
#pragma unroll
    for (int cb = 0; cb < 4; cb++) {
#pragma unroll
        for (int r = 0; r < 4; r++) {
            int t = w * 16 + q * 4 + r;
            int s = cb * 16 + mm;
            float g = (s <= t) ? P[cb][r] * __expf(cum_s[t] - cum_s[s]) * dt_s[s] : 0.f;
            G[t][s] = f2bf(g);
        }
    }
    __syncthreads();

    floatx4 Y[4];
#pragma unroll
    for (int i = 0; i < 4; i++) Y[i] = (floatx4){0.f, 0.f, 0.f, 0.f};
#pragma unroll
    for (int kk = 0; kk < 2; kk++) {
        short8 a = *(const short8*)&G[w * 16 + mm][kk * 32 + q * 8];
#pragma unroll
        for (int cb = 0; cb < 4; cb++) {
            short8 b = *(const short8*)&Xt[cb * 16 + mm][kk * 32 + q * 8];
            Y[cb] = __builtin_amdgcn_mfma_f32_16x16x32_bf16(a, b, Y[cb], 0, 0, 0);
        }
    }
    const short* Hc = Hprev + (size_t)blk * 8192;
#pragma unroll
    for (int kk = 0; kk < 4; kk++) {
        short8 a = *(const short8*)&Ct[w * 16 + mm][kk * 32 + q * 8];
#pragma unroll
        for (int cb = 0; cb < 4; cb++) {
            short8 b = *(const short8*)(Hc + (size_t)(cb * 16 + mm) * DSTATE + kk * 32 + q * 8);
            Y[cb] = __builtin_amdgcn_mfma_f32_16x16x32_bf16(a, b, Y[cb], 0, 0, 0);
        }
    }
#pragma unroll
    for (int cb = 0; cb < 4; cb++)
#pragma unroll
        for (int r = 0; r < 4; r++)
            Yb[(size_t)(base_row + w * 16 + q * 4 + r) * DINNER + hh * 64 + cb * 16 + mm] =
                __float2bfloat16(Y[cb][r]);
}

// ---------------------------------------------------------------- gating + RMSNorm (192 thr x 8 ch)
__global__ __launch_bounds__(192) void gate_kernel(const __hip_bfloat16* __restrict__ Yb,
                                                   const __hip_bfloat16* __restrict__ xh,
                                                   const __hip_bfloat16* __restrict__ Zb,
                                                   const float* __restrict__ Dp,
                                                   const float* __restrict__ norm_w,
                                                   __hip_bfloat16* __restrict__ A2) {
    int row = blockIdx.x;
    int dir = row >> 12;
    int c8 = threadIdx.x * 8;
    int hd = c8 >> 6;
    const short* yr = (const short*)Yb + (size_t)row * DINNER + c8;
    const short* xr = (const short*)xh + (size_t)row * DINNER + c8;
    const short* zr = (const short*)Zb + (size_t)row * DINNER + c8;

    short8 y8 = *(const short8*)yr;
    short8 x8 = *(const short8*)xr;
    short8 z8 = *(const short8*)zr;
    float Dv = Dp[dir * NH + hd];

    float vals[8];
    float ss = 0.f;
#pragma unroll
    for (int j = 0; j < 8; j++) {
        float v = bf2f(y8[j]) + Dv * bf2f(x8[j]);
        float z = bf2f(z8[j]);
        v *= z / (1.f + __expf(-z));
        vals[j] = v;
        ss += v * v;
    }
#pragma unroll
    for (int off = 32; off; off >>= 1) ss += __shfl_down(ss, off);
    __shared__ float ls[3];
    if ((threadIdx.x & 63) == 0) ls[threadIdx.x >> 6] = ss;
    __syncthreads();
    float tot = ls[0] + ls[1] + ls[2];
    float scale = rsqrtf(tot / (float)DINNER + 1e-5f);

    const float* nw = norm_w + dir * DINNER + c8;
    short8 o;
#pragma unroll
    for (int j = 0; j < 8; j++) o[j] = f2bf(vals[j] * scale * nw[j]);
    *(short8*)((short*)A2 + (size_t)row * DINNER + c8) = o;
}

// ---------------------------------------------------------------- launch
extern "C" void kernel_launch(void* const* d_in, const int* in_sizes, int n_in,
                              void* d_out, int out_size, void* d_ws, size_t ws_size,
                              hipStream_t stream) {
    const float* x        = (const float*)d_in[0];
    const float* in_w     = (const float*)d_in[1];
    const float* conv_w   = (const float*)d_in[2];
    const float* conv_b   = (const float*)d_in[3];
    const float* dt_bias  = (const float*)d_in[4];
    const float* A_log    = (const float*)d_in[5];
    const float* Dp       = (const float*)d_in[6];
    const float* norm_w   = (const float*)d_in[7];
    const float* out_w    = (const float*)d_in[8];
    float* out = (float*)d_out;

    const size_t szW2 = (size_t)2 * DMODEL * DINNER * 2;
    const size_t szZ  = (size_t)8192 * DINNER * 2;
    const size_t szXH = (size_t)8192 * DINNER * 2;
    const size_t szBM = (size_t)8192 * DSTATE * 2;
    const size_t szCM = szBM;
    const size_t szDT = (size_t)8192 * NH * 4;
    const size_t szLA = szDT;
    const size_t szA1 = (size_t)4096 * DMODEL * 2;     // unflipped, shared by both dirs
    const size_t szW1 = (size_t)2 * NPROJ * DMODEL * 2;
    const size_t szXB = (size_t)8192 * CONVDIM * 2;
    const size_t szYb = (size_t)8192 * DINNER * 2;
    const size_t szSS = (size_t)96 * NCH * 8192 * 2;
    const size_t szRa = szA1 + szW1 + szXB;
    size_t szR = szRa;
    if (szR < szYb) szR = szYb;
    if (szR < szSS) szR = szSS;
    const size_t szHp = szSS;
    const size_t szCU = (size_t)96 * SEQ * 4;

    char* ws = (char*)d_ws;
    size_t off = 0;
    auto alloc = [&](size_t bytes) { char* p = ws + off; off += (bytes + 255) & ~(size_t)255; return p; };

    __hip_bfloat16* W2 = (__hip_bfloat16*)alloc(szW2);
    __hip_bfloat16* Z  = (__hip_bfloat16*)alloc(szZ);
    __hip_bfloat16* XH = (__hip_bfloat16*)alloc(szXH);
    __hip_bfloat16* BM = (__hip_bfloat16*)alloc(szBM);
    __hip_bfloat16* CM = (__hip_bfloat16*)alloc(szCM);
    float* DT = (float*)alloc(szDT);
    float* LA = (float*)alloc(szLA);
    char*  R  = (char*)alloc(szR);
    __hip_bfloat16* A1  = (__hip_bfloat16*)R;
    __hip_bfloat16* W1  = (__hip_bfloat16*)(R + szA1);
    __hip_bfloat16* XBC = (__hip_bfloat16*)(R + szA1 + szW1);
    short* SS = (short*)R;
    __hip_bfloat16* Yb = (__hip_bfloat16*)R;

    short* Hp = (short*)alloc(szHp);
    float* CU = (float*)alloc(szCU);
    if (off > ws_size) return;   // clean fail instead of OOB crash

    // 1. fused converts: weights + x (A1 rows = b*SEQ+t, unflipped)
    int n1 = 2 * NPROJ * DMODEL / 4;
    int n2 = 2 * DMODEL * DINNER / 4;
    int n3 = 4096 * DMODEL / 4;
    cvt3_kernel<<<(n1 + n2 + n3 + 255) / 256, 256, 0, stream>>>(in_w, W1, n1, out_w, W2, n2, x, A1, n3);

    // 2. in_proj GEMM: 64x128 tiles, both dirs fused (z = dir), dir1 flips A rows in-gather
    {
        dim3 grid(4096 / 64, (NPROJ + 127) / 128, 2);
        gemm_bt<<<grid, 256, 0, stream>>>(A1, 0,
                                          W1, (size_t)NPROJ * DMODEL,
                                          nullptr, Z, XBC, DT, LA, dt_bias, A_log,
                                          4096, NPROJ, DMODEL, 1, 2, 1);
    }

    // 3. conv + silu
    conv_kernel<<<4 * 128, 256, 0, stream>>>(XBC, conv_w, conv_b, XH, BM, CM);

    // 4. SSD chunked scan (3-pass)
    ssd1_kernel<<<4 * NH * NCH, 256, 0, stream>>>(XH, BM, DT, LA, SS, CU);
    ssd2_kernel<<<4 * NH * 4, 256, 0, stream>>>(SS, CU, Hp);
    ssd3_kernel<<<4 * NH * NCH, 256, 0, stream>>>(XH, BM, CM, DT, CU, Hp, Yb);

    // 5. gating + RMSNorm (A2 == Z, in-place)
    gate_kernel<<<2 * 4096, 192, 0, stream>>>(Yb, XH, Z, Dp, norm_w, Z);

    // 6. out_proj: zero-init + single launch (z = dir*2 + kslice), atomic adds, dir1 flips C rows
    hipMemsetAsync(out, 0, (size_t)4096 * DMODEL * 4, stream);
    {
        dim3 grid(4096 / 64, DMODEL / 128, 4);
        gemm_bt<<<grid, 256, 0, stream>>>(Z, (size_t)4096 * DINNER,
                                          W2, (size_t)DMODEL * DINNER,
                                          out, nullptr, nullptr, nullptr, nullptr, nullptr, nullptr,
                                          4096, DMODEL, DINNER, 2, 1, 0);
    }
}

// Round 5
// 353.692 us; speedup vs baseline: 1.2357x; 1.0880x over previous
//
#include <hip/hip_runtime.h>
#include <hip/hip_bf16.h>

typedef __attribute__((ext_vector_type(8))) short short8;
typedef __attribute__((ext_vector_type(4))) short bfx4;
typedef __attribute__((ext_vector_type(4))) float floatx4;

#define SEQ     2048
#define DMODEL  768
#define DINNER  1536
#define DSTATE  128
#define NH      24
#define CONVDIM 1792
#define NPROJ   3352   // 2*DINNER + 2*DSTATE + NH
#define QCH     64     // SSD chunk length
#define NCH     (SEQ / QCH)   // 32 chunks

__device__ inline float bf2f(short s) {
    return __uint_as_float(((unsigned)(unsigned short)s) << 16);
}
__device__ inline short f2bf(float f) {
    __hip_bfloat16 h = __float2bfloat16(f);
    return *reinterpret_cast<short*>(&h);
}
__device__ inline void gl_lds16(const void* g, void* l) {
    __builtin_amdgcn_global_load_lds((const __attribute__((address_space(1))) unsigned int*)g,
                                     (__attribute__((address_space(3))) unsigned int*)l, 16, 0, 0);
}

// ---------------------------------------------------------------- fused converts (float4), 3 segments
__global__ __launch_bounds__(256) void cvt3_kernel(const float* __restrict__ s1, __hip_bfloat16* __restrict__ d1, int n1,
                                                   const float* __restrict__ s2, __hip_bfloat16* __restrict__ d2, int n2,
                                                   const float* __restrict__ s3, __hip_bfloat16* __restrict__ d3, int n3) {
    int i = blockIdx.x * 256 + threadIdx.x;
    const float* src; __hip_bfloat16* dst; int idx;
    if (i < n1)                { src = s1; dst = d1; idx = i; }
    else if (i < n1 + n2)      { src = s2; dst = d2; idx = i - n1; }
    else if (i < n1 + n2 + n3) { src = s3; dst = d3; idx = i - n1 - n2; }
    else return;
    float4 v = *(const float4*)(src + (size_t)idx * 4);
    bfx4 o = { f2bf(v.x), f2bf(v.y), f2bf(v.z), f2bf(v.w) };
    *(bfx4*)((short*)dst + (size_t)idx * 4) = o;
}

// ---------------------------------------------------------------- GEMM 64x128 tile, BK=32, 4 waves, double-buffered
// R4 finding: BOTH gemm dispatches finish exactly at WRITE_SIZE / ~540 GB/s — the fine-granule
// write/atomic path is the suspected wall, not MFMA/staging/occupancy (all slack).
// This round: epilogue-only changes (K-loop byte-identical to the measured R4 kernel):
//  mode 2 (in_proj): LDS-transpose epilogue -> coalesced short8 stores (256B/row segments)
//                    instead of 28M scalar 2B stores. dt-head block keeps scalar path.
//  mode 1 (out_proj): plain fp32 stores of per-slice partials into workspace (NO atomics,
//                    no memset); reduce4_kernel sums 4 slices (flipping dir1 rows).
__global__ __launch_bounds__(256) void gemm_bt(const __hip_bfloat16* __restrict__ Abase, size_t aStride,
                                               const __hip_bfloat16* __restrict__ Bbase, size_t bStride,
                                               float* __restrict__ C,
                                               __hip_bfloat16* __restrict__ Zb,
                                               __hip_bfloat16* __restrict__ Xb,
                                               float* __restrict__ DT,
                                               float* __restrict__ LA,
                                               const float* __restrict__ dtbias,
                                               const float* __restrict__ Alog,
                                               int M, int N, int K, int zdiv, int mode, int flipA) {
    __shared__ short As[2][32 * 64];   // 4 KB per buf: 32 lines x 128 B (rows l & l+32 packed)
    __shared__ short Bs[2][64 * 64];   // 8 KB per buf: 64 lines x 128 B (rows l & l+64 packed)
    __shared__ short Tr[32][136];      // transpose staging for coalesced epilogue stores
    int tid = threadIdx.x;
    int w = tid >> 6, lane = tid & 63;
    int q = lane >> 4, mm = lane & 15;
    int wm = w >> 1, wn = w & 1;       // wave tile 32x64 within 64x128 block tile
    int m0 = blockIdx.x * 64, n0 = blockIdx.y * 128;
    int z = blockIdx.z;
    int dir = z / zdiv, ks = z - dir * zdiv;
    int kl = K / zdiv;
    int kbeg = ks * kl;
    const short* Ag = (const short*)Abase + (size_t)dir * aStride;
    const short* Bg = (const short*)Bbase + (size_t)dir * bStride;
    int fA = flipA && dir;

    // A staging: 4 waves x 8 lines = 32 lines, 1 load/thread
    size_t aoff; int aldso;
    {
        int ln = w * 8 + (lane >> 3);    // line 0..31
        int s  = lane & 7;               // slot within line
        int c  = s ^ (ln & 7);
        int row = (c < 4) ? ln : ln + 32;
        int ch  = (c < 4) ? c : (c ^ 4);
        int ar = m0 + row;
        if (fA) { int bb = ar >> 11, tt = ar & 2047; ar = (bb << 11) + (2047 - tt); }
        aoff = (size_t)ar * K + ch * 8;
        aldso = w * 1024;                // bytes
    }
    // B staging: 8 windows (w*2+j) x 8 lines = 64 lines, 2 loads/thread
    size_t boff[2];
    int bldso[2];
#pragma unroll
    for (int j = 0; j < 2; j++) {
        int widx = w * 2 + j;            // 0..7
        int ln = widx * 8 + (lane >> 3); // line 0..63
        int s  = lane & 7;
        int c  = s ^ (ln & 7);
        int row = (c < 4) ? ln : ln + 64;
        int ch  = (c < 4) ? c : (c ^ 4);
        int br = n0 + row; if (br > N - 1) br = N - 1;   // dup rows; cols skipped on store
        boff[j] = (size_t)br * K + ch * 8;
        bldso[j] = widx * 1024;          // bytes
    }

    floatx4 acc[8];
#pragma unroll
    for (int i = 0; i < 8; i++) acc[i] = (floatx4){0.f, 0.f, 0.f, 0.f};

    int niter = kl / 32;
    auto stage = [&](int buf, int k0) {
        gl_lds16(Ag + aoff + kbeg + k0, (char*)&As[buf][0] + aldso);
        gl_lds16(Bg + boff[0] + kbeg + k0, (char*)&Bs[buf][0] + bldso[0]);
        gl_lds16(Bg + boff[1] + kbeg + k0, (char*)&Bs[buf][0] + bldso[1]);
    };
    stage(0, 0);
    int slotA = (q ^ (mm & 7) ^ (wm << 2)) * 8;   // elements
    int slotB = (q ^ (mm & 7) ^ (wn << 2)) * 8;
    for (int it = 0; it < niter; it++) {
        __syncthreads();                           // buf[it&1] staged; prior reads done
        if (it + 1 < niter) stage((it + 1) & 1, (it + 1) * 32);
        const short* Ab = &As[it & 1][0];
        const short* Bb = &Bs[it & 1][0];
        short8 af[2], bfr[4];
#pragma unroll
        for (int mb = 0; mb < 2; mb++)
            af[mb] = *(const short8*)&Ab[(mb * 16 + mm) * 64 + slotA];
#pragma unroll
        for (int nb = 0; nb < 4; nb++)
            bfr[nb] = *(const short8*)&Bb[(nb * 16 + mm) * 64 + slotB];
#pragma unroll
        for (int mb = 0; mb < 2; mb++)
#pragma unroll
            for (int nb = 0; nb < 4; nb++)
                acc[mb * 4 + nb] = __builtin_amdgcn_mfma_f32_16x16x32_bf16(af[mb], bfr[nb], acc[mb * 4 + nb], 0, 0, 0);
    }

    if (mode == 1) {
        // out_proj: plain fp32 partial store into slice z of workspace C (no atomics, no flip)
        float* Cz = C + (size_t)z * 4096 * 768;
#pragma unroll
        for (int mb = 0; mb < 2; mb++)
#pragma unroll
            for (int nb = 0; nb < 4; nb++) {
                int col = n0 + wn * 64 + nb * 16 + mm;
#pragma unroll
                for (int r = 0; r < 4; r++) {
                    int rr = m0 + wm * 32 + mb * 16 + q * 4 + r;
                    Cz[(size_t)rr * 768 + col] = acc[mb * 4 + nb][r];
                }
            }
        return;
    }

    __hip_bfloat16* Zb2 = Zb + (size_t)dir * 4096 * DINNER;
    __hip_bfloat16* Xb2 = Xb + (size_t)dir * 4096 * CONVDIM;

    if (n0 + 128 <= DINNER + CONVDIM) {
        // fast path: whole 128-col block lands in one bf16 region -> transpose + coalesced stores
        short* dstBase; int ldd, c0;
        if (n0 < DINNER) { dstBase = (short*)Zb2; ldd = DINNER; c0 = n0; }
        else             { dstBase = (short*)Xb2; ldd = CONVDIM; c0 = n0 - DINNER; }
#pragma unroll
        for (int p = 0; p < 2; p++) {
            __syncthreads();
            if (wm == p) {
#pragma unroll
                for (int mb = 0; mb < 2; mb++)
#pragma unroll
                    for (int nb = 0; nb < 4; nb++)
#pragma unroll
                        for (int r = 0; r < 4; r++)
                            Tr[mb * 16 + q * 4 + r][wn * 64 + nb * 16 + mm] =
                                f2bf(acc[mb * 4 + nb][r]);
            }
            __syncthreads();
            int row = tid >> 3, c16 = (tid & 7) * 16;
            short8 v0 = *(const short8*)&Tr[row][c16];
            short8 v1 = *(const short8*)&Tr[row][c16 + 8];
            short* dp = dstBase + (size_t)(m0 + p * 32 + row) * ldd + c0 + c16;
            *(short8*)dp = v0;
            *(short8*)(dp + 8) = v1;
        }
        return;
    }

    // dt-head block (n0 == DINNER+CONVDIM): scalar path with softplus
    float* DT2 = DT + (size_t)dir * 4096 * NH;
    float* LA2 = LA + (size_t)dir * 4096 * NH;
    const float* dtb2 = dtbias + dir * NH;
    const float* Al2  = Alog + dir * NH;
#pragma unroll
    for (int mb = 0; mb < 2; mb++) {
#pragma unroll
        for (int nb = 0; nb < 4; nb++) {
            int col = n0 + wn * 64 + nb * 16 + mm;
            if (col >= N) continue;
#pragma unroll
            for (int r = 0; r < 4; r++) {
                int rr = m0 + wm * 32 + mb * 16 + q * 4 + r;
                float v = acc[mb * 4 + nb][r];
                int hh = col - (DINNER + CONVDIM);
                float raw = v + dtb2[hh];
                float dtv = (raw > 20.f) ? raw : log1pf(__expf(raw));
                float Av  = -__expf(Al2[hh]);
                DT2[(size_t)rr * NH + hh] = dtv;
                LA2[(size_t)rr * NH + hh] = dtv * Av;
            }
        }
    }
}

// ---------------------------------------------------------------- out_proj reduce: out = P0+P1+flip(P2+P3)
__global__ __launch_bounds__(256) void reduce4_kernel(const float* __restrict__ P, float* __restrict__ out) {
    int idx = blockIdx.x * 256 + threadIdx.x;   // 4096*192 float4 slots
    int row = idx / 192, c4 = idx - row * 192;
    int b = row >> 11, t = row & 2047;
    int fr = (b << 11) + (2047 - t);
    const size_t sl = (size_t)4096 * 192;
    const float4* P4 = (const float4*)P;
    float4 a = P4[(size_t)row * 192 + c4];
    float4 bb = P4[sl + (size_t)row * 192 + c4];
    float4 c = P4[2 * sl + (size_t)fr * 192 + c4];
    float4 d = P4[3 * sl + (size_t)fr * 192 + c4];
    float4 o = { a.x + bb.x + c.x + d.x, a.y + bb.y + c.y + d.y,
                 a.z + bb.z + c.z + d.z, a.w + bb.w + c.w + d.w };
    ((float4*)out)[(size_t)row * 192 + c4] = o;
}

// ---------------------------------------------------------------- conv (depthwise K=4) + silu
__global__ __launch_bounds__(256) void conv_kernel(const __hip_bfloat16* __restrict__ Xb,
                                                   const float* __restrict__ conv_w,
                                                   const float* __restrict__ conv_b,
                                                   __hip_bfloat16* __restrict__ xh,
                                                   __hip_bfloat16* __restrict__ Bm,
                                                   __hip_bfloat16* __restrict__ Cm) {
    int db  = blockIdx.x >> 7;
    int dir = db >> 1;
    int t0  = (blockIdx.x & 127) * 16;
    int c8  = threadIdx.x * 8;
    if (c8 >= CONVDIM) return;

    float wk[4][8], bs[8];
#pragma unroll
    for (int j = 0; j < 8; j++) {
        bs[j] = conv_b[dir * CONVDIM + c8 + j];
#pragma unroll
        for (int k = 0; k < 4; k++) wk[k][j] = conv_w[((size_t)dir * CONVDIM + c8 + j) * 4 + k];
    }

    const short* xrow = (const short*)Xb + (size_t)db * SEQ * CONVDIM + c8;
    short8 win[4];
    const short8 zer = {0, 0, 0, 0, 0, 0, 0, 0};
#pragma unroll
    for (int k = 0; k < 3; k++) {
        int ts = t0 - 3 + k;
        win[k] = (ts >= 0) ? *(const short8*)(xrow + (size_t)ts * CONVDIM) : zer;
    }

    for (int tt = 0; tt < 16; tt++) {
        int t = t0 + tt;
        win[3] = *(const short8*)(xrow + (size_t)t * CONVDIM);
        short8 outv;
#pragma unroll
        for (int j = 0; j < 8; j++) {
            float acc = bs[j];
#pragma unroll
            for (int k = 0; k < 4; k++) acc += wk[k][j] * bf2f(win[k][j]);
            float sv = acc / (1.f + __expf(-acc));
            outv[j] = f2bf(sv);
        }
        if (c8 < DINNER)
            *(short8*)((short*)xh + (size_t)(db * SEQ + t) * DINNER + c8) = outv;
        else if (c8 < DINNER + DSTATE)
            *(short8*)((short*)Bm + (size_t)(db * SEQ + t) * DSTATE + (c8 - DINNER)) = outv;
        else
            *(short8*)((short*)Cm + (size_t)(db * SEQ + t) * DSTATE + (c8 - DINNER - DSTATE)) = outv;
        win[0] = win[1]; win[1] = win[2]; win[2] = win[3];
    }
}

// ---------------------------------------------------------------- SSD pass 1
__global__ __launch_bounds__(256) void ssd1_kernel(const __hip_bfloat16* __restrict__ XH,
                                                   const __hip_bfloat16* __restrict__ BMh,
                                                   const float* __restrict__ DT,
                                                   const float* __restrict__ LA,
                                                   short* __restrict__ SS,
                                                   float* __restrict__ CUM) {
    int blk = blockIdx.x;
    int ck = blk & 31;
    int dbh = blk >> 5;
    int hh = dbh % NH, db = dbh / NH;
    int base_row = db * SEQ + ck * QCH;

    __shared__ float cum_s[QCH], dt_s[QCH];
    __shared__ short Xt[64][72];
    __shared__ short Bt[128][72];

    int tid = threadIdx.x;
    int lane = tid & 63, w = tid >> 6;
    int q = lane >> 4, mm = lane & 15;

    if (tid < QCH) {
        float la  = LA[(size_t)(base_row + tid) * NH + hh];
        float dtv = DT[(size_t)(base_row + tid) * NH + hh];
        float cs = la;
#pragma unroll
        for (int d = 1; d < 64; d <<= 1) {
            float u = __shfl_up(cs, d);
            if (tid >= d) cs += u;
        }
        cum_s[tid] = cs;
        dt_s[tid] = dtv;
        CUM[(size_t)dbh * SEQ + ck * QCH + tid] = cs;
    }
    __syncthreads();
    float cumL = cum_s[QCH - 1];

    {
        int s2 = (tid & 31) * 2, pb = tid >> 5;
        float f0 = dt_s[s2]     * __expf(cumL - cum_s[s2]);
        float f1 = dt_s[s2 + 1] * __expf(cumL - cum_s[s2 + 1]);
        const short* r0 = (const short*)XH + (size_t)(base_row + s2) * DINNER + hh * 64 + pb * 8;
        const short* r1 = r0 + DINNER;
        short8 x0 = *(const short8*)r0;
        short8 x1 = *(const short8*)r1;
#pragma unroll
        for (int j = 0; j < 8; j++) {
            unsigned lo = (unsigned short)f2bf(f0 * bf2f(x0[j]));
            unsigned hi = (unsigned short)f2bf(f1 * bf2f(x1[j]));
            *(unsigned*)&Xt[pb * 8 + j][s2] = lo | (hi << 16);
        }
    }
    {
        int s2 = (tid & 31) * 2, nb = tid >> 5;
        const short* r0 = (const short*)BMh + (size_t)(base_row + s2) * DSTATE + nb * 16;
        const short* r1 = r0 + DSTATE;
        short8 b0a = *(const short8*)r0,  b0b = *(const short8*)(r0 + 8);
        short8 b1a = *(const short8*)r1,  b1b = *(const short8*)(r1 + 8);
#pragma unroll
        for (int j = 0; j < 8; j++) {
            *(unsigned*)&Bt[nb * 16 + j][s2] =
                (unsigned)(unsigned short)b0a[j] | ((unsigned)(unsigned short)b1a[j] << 16);
            *(unsigned*)&Bt[nb * 16 + 8 + j][s2] =
                (unsigned)(unsigned short)b0b[j] | ((unsigned)(unsigned short)b1b[j] << 16);
        }
    }
    __syncthreads();

    floatx4 acc[8];
#pragma unroll
    for (int i = 0; i < 8; i++) acc[i] = (floatx4){0.f, 0.f, 0.f, 0.f};
#pragma unroll
    for (int kk = 0; kk < 2; kk++) {
        short8 a = *(const short8*)&Xt[w * 16 + mm][kk * 32 + q * 8];
#pragma unroll
        for (int cb = 0; cb < 8; cb++) {
            short8 b = *(const short8*)&Bt[cb * 16 + mm][kk * 32 + q * 8];
            acc[cb] = __builtin_amdgcn_mfma_f32_16x16x32_bf16(a, b, acc[cb], 0, 0, 0);
        }
    }
    short* Sp = SS + (size_t)blk * 8192;
#pragma unroll
    for (int cb = 0; cb < 8; cb++)
#pragma unroll
        for (int r = 0; r < 4; r++)
            Sp[(w * 16 + q * 4 + r) * DSTATE + cb * 16 + mm] = f2bf(acc[cb][r]);
}

// ---------------------------------------------------------------- SSD pass 2: inter-chunk scan
__global__ __launch_bounds__(256) void ssd2_kernel(const short* __restrict__ SS,
                                                   const float* __restrict__ CUM,
                                                   short* __restrict__ Hprev) {
    int blk = blockIdx.x;
    int dbh = blk >> 2, part = blk & 3;
    int off = part * 2048 + threadIdx.x * 8;
    size_t base = (size_t)dbh * NCH * 8192 + off;
    float h[8];
#pragma unroll
    for (int j = 0; j < 8; j++) h[j] = 0.f;
    for (int c = 0; c < NCH; c++) {
        float W = __expf(CUM[(size_t)dbh * SEQ + c * QCH + QCH - 1]);
        size_t p = base + (size_t)c * 8192;
        short8 s = *(const short8*)(SS + p);
        short8 o;
#pragma unroll
        for (int j = 0; j < 8; j++) o[j] = f2bf(h[j]);
        *(short8*)(Hprev + p) = o;
#pragma unroll
        for (int j = 0; j < 8; j++) h[j] = fmaf(h[j], W, bf2f(s[j]));
    }
}

// ---------------------------------------------------------------- SSD pass 3
__global__ __launch_bounds__(256) void ssd3_kernel(const __hip_bfloat16* __restrict__ XH,
                                                   const __hip_bfloat16* __restrict__ BMh,
                                                   const __hip_bfloat16* __restrict__ CMh,
                                                   const float* __restrict__ DT,
                                                   const float* __restrict__ CUM,
                                                   const short* __restrict__ Hprev,
                                                   __hip_bfloat16* __restrict__ Yb) {
    int blk = blockIdx.x;
    int ck = blk & 31;
    int dbh = blk >> 5;
    int hh = dbh % NH, db = dbh / NH;
    int base_row = db * SEQ + ck * QCH;

    __shared__ float cum_s[QCH], dt_s[QCH];
    __shared__ short Ct[64][136];
    __shared__ short G[64][72];
    __shared__ short Xt[64][72];

    int tid = threadIdx.x;
    int lane = tid & 63, w = tid >> 6;
    int q = lane >> 4, mm = lane & 15;

    if (tid < QCH) {
        cum_s[tid] = CUM[(size_t)dbh * SEQ + ck * QCH + tid];
        dt_s[tid]  = DT[(size_t)(base_row + tid) * NH + hh];
    }

    const short* Cg = (const short*)CMh + (size_t)base_row * DSTATE;
    const short* Bg = (const short*)BMh + (size_t)base_row * DSTATE;
    floatx4 P[4];
#pragma unroll
    for (int i = 0; i < 4; i++) P[i] = (floatx4){0.f, 0.f, 0.f, 0.f};
#pragma unroll
    for (int kk = 0; kk < 4; kk++) {
        short8 a = *(const short8*)(Cg + (size_t)(w * 16 + mm) * DSTATE + kk * 32 + q * 8);
#pragma unroll
        for (int cb = 0; cb < 4; cb++) {
            short8 b = *(const short8*)(Bg + (size_t)(cb * 16 + mm) * DSTATE + kk * 32 + q * 8);
            P[cb] = __builtin_amdgcn_mfma_f32_16x16x32_bf16(a, b, P[cb], 0, 0, 0);
        }
    }
    __syncthreads();

    {
        int t = tid & 63, nb4 = tid >> 6;
        float wt = __expf(cum_s[t]);
        const short* src = Cg + (size_t)t * DSTATE + nb4 * 32;
#pragma unroll
        for (int u = 0; u < 2; u++) {
            short8 v = *(const short8*)(src + u * 16);
            short8 v2 = *(const short8*)(src + u * 16 + 8);
#pragma unroll
            for (int j = 0; j < 4; j++) {
                unsigned lo = (unsigned short)f2bf(wt * bf2f(v[2 * j]));
                unsigned hi = (unsigned short)f2bf(wt * bf2f(v[2 * j + 1]));
                *(unsigned*)&Ct[t][nb4 * 32 + u * 16 + 2 * j] = lo | (hi << 16);
                lo = (unsigned short)f2bf(wt * bf2f(v2[2 * j]));
                hi = (unsigned short)f2bf(wt * bf2f(v2[2 * j + 1]));
                *(unsigned*)&Ct[t][nb4 * 32 + u * 16 + 8 + 2 * j] = lo | (hi << 16);
            }
        }
    }
    {
        int s2 = (tid & 31) * 2, pb = tid >> 5;
        const short* r0 = (const short*)XH + (size_t)(base_row + s2) * DINNER + hh * 64 + pb * 8;
        const short* r1 = r0 + DINNER;
        short8 x0 = *(const short8*)r0;
        short8 x1 = *(const short8*)r1;
#pragma unroll
        for (int j = 0; j < 8; j++) {
            *(unsigned*)&Xt[pb * 8 + j][s2] =
                (unsigned)(unsigned short)x0[j] | ((unsigned)(unsigned short)x1[j] << 16);
        }
    }
#pragma unroll
    for (int cb = 0; cb < 4; cb++) {
#pragma unroll
        for (int r = 0; r < 4; r++) {
            int t = w * 16 + q * 4 + r;
            int s = cb * 16 + mm;
            float g = (s <= t) ? P[cb][r] * __expf(cum_s[t] - cum_s[s]) * dt_s[s] : 0.f;
            G[t][s] = f2bf(g);
        }
    }
    __syncthreads();

    floatx4 Y[4];
#pragma unroll
    for (int i = 0; i < 4; i++) Y[i] = (floatx4){0.f, 0.f, 0.f, 0.f};
#pragma unroll
    for (int kk = 0; kk < 2; kk++) {
        short8 a = *(const short8*)&G[w * 16 + mm][kk * 32 + q * 8];
#pragma unroll
        for (int cb = 0; cb < 4; cb++) {
            short8 b = *(const short8*)&Xt[cb * 16 + mm][kk * 32 + q * 8];
            Y[cb] = __builtin_amdgcn_mfma_f32_16x16x32_bf16(a, b, Y[cb], 0, 0, 0);
        }
    }
    const short* Hc = Hprev + (size_t)blk * 8192;
#pragma unroll
    for (int kk = 0; kk < 4; kk++) {
        short8 a = *(const short8*)&Ct[w * 16 + mm][kk * 32 + q * 8];
#pragma unroll
        for (int cb = 0; cb < 4; cb++) {
            short8 b = *(const short8*)(Hc + (size_t)(cb * 16 + mm) * DSTATE + kk * 32 + q * 8);
            Y[cb] = __builtin_amdgcn_mfma_f32_16x16x32_bf16(a, b, Y[cb], 0, 0, 0);
        }
    }
#pragma unroll
    for (int cb = 0; cb < 4; cb++)
#pragma unroll
        for (int r = 0; r < 4; r++)
            Yb[(size_t)(base_row + w * 16 + q * 4 + r) * DINNER + hh * 64 + cb * 16 + mm] =
                __float2bfloat16(Y[cb][r]);
}

// ---------------------------------------------------------------- gating + RMSNorm (192 thr x 8 ch)
__global__ __launch_bounds__(192) void gate_kernel(const __hip_bfloat16* __restrict__ Yb,
                                                   const __hip_bfloat16* __restrict__ xh,
                                                   const __hip_bfloat16* __restrict__ Zb,
                                                   const float* __restrict__ Dp,
                                                   const float* __restrict__ norm_w,
                                                   __hip_bfloat16* __restrict__ A2) {
    int row = blockIdx.x;
    int dir = row >> 12;
    int c8 = threadIdx.x * 8;
    int hd = c8 >> 6;
    const short* yr = (const short*)Yb + (size_t)row * DINNER + c8;
    const short* xr = (const short*)xh + (size_t)row * DINNER + c8;
    const short* zr = (const short*)Zb + (size_t)row * DINNER + c8;

    short8 y8 = *(const short8*)yr;
    short8 x8 = *(const short8*)xr;
    short8 z8 = *(const short8*)zr;
    float Dv = Dp[dir * NH + hd];

    float vals[8];
    float ss = 0.f;
#pragma unroll
    for (int j = 0; j < 8; j++) {
        float v = bf2f(y8[j]) + Dv * bf2f(x8[j]);
        float z = bf2f(z8[j]);
        v *= z / (1.f + __expf(-z));
        vals[j] = v;
        ss += v * v;
    }
#pragma unroll
    for (int off = 32; off; off >>= 1) ss += __shfl_down(ss, off);
    __shared__ float ls[3];
    if ((threadIdx.x & 63) == 0) ls[threadIdx.x >> 6] = ss;
    __syncthreads();
    float tot = ls[0] + ls[1] + ls[2];
    float scale = rsqrtf(tot / (float)DINNER + 1e-5f);

    const float* nw = norm_w + dir * DINNER + c8;
    short8 o;
#pragma unroll
    for (int j = 0; j < 8; j++) o[j] = f2bf(vals[j] * scale * nw[j]);
    *(short8*)((short*)A2 + (size_t)row * DINNER + c8) = o;
}

// ---------------------------------------------------------------- launch
extern "C" void kernel_launch(void* const* d_in, const int* in_sizes, int n_in,
                              void* d_out, int out_size, void* d_ws, size_t ws_size,
                              hipStream_t stream) {
    const float* x        = (const float*)d_in[0];
    const float* in_w     = (const float*)d_in[1];
    const float* conv_w   = (const float*)d_in[2];
    const float* conv_b   = (const float*)d_in[3];
    const float* dt_bias  = (const float*)d_in[4];
    const float* A_log    = (const float*)d_in[5];
    const float* Dp       = (const float*)d_in[6];
    const float* norm_w   = (const float*)d_in[7];
    const float* out_w    = (const float*)d_in[8];
    float* out = (float*)d_out;

    const size_t szW2 = (size_t)2 * DMODEL * DINNER * 2;
    const size_t szZ  = (size_t)8192 * DINNER * 2;
    const size_t szXH = (size_t)8192 * DINNER * 2;
    const size_t szBM = (size_t)8192 * DSTATE * 2;
    const size_t szCM = szBM;
    const size_t szDT = (size_t)8192 * NH * 4;
    const size_t szLA = szDT;
    const size_t szA1 = (size_t)4096 * DMODEL * 2;     // unflipped, shared by both dirs
    const size_t szW1 = (size_t)2 * NPROJ * DMODEL * 2;
    const size_t szXB = (size_t)8192 * CONVDIM * 2;
    const size_t szYb = (size_t)8192 * DINNER * 2;
    const size_t szSS = (size_t)96 * NCH * 8192 * 2;   // 50.33 MB
    const size_t szCp = (size_t)4 * 4096 * 768 * 4;    // 50.33 MB (== szSS, reuses R)
    const size_t szRa = szA1 + szW1 + szXB;
    size_t szR = szRa;
    if (szR < szYb) szR = szYb;
    if (szR < szSS) szR = szSS;
    if (szR < szCp) szR = szCp;
    const size_t szHp = szSS;
    const size_t szCU = (size_t)96 * SEQ * 4;

    char* ws = (char*)d_ws;
    size_t off = 0;
    auto alloc = [&](size_t bytes) { char* p = ws + off; off += (bytes + 255) & ~(size_t)255; return p; };

    __hip_bfloat16* W2 = (__hip_bfloat16*)alloc(szW2);
    __hip_bfloat16* Z  = (__hip_bfloat16*)alloc(szZ);
    __hip_bfloat16* XH = (__hip_bfloat16*)alloc(szXH);
    __hip_bfloat16* BM = (__hip_bfloat16*)alloc(szBM);
    __hip_bfloat16* CM = (__hip_bfloat16*)alloc(szCM);
    float* DT = (float*)alloc(szDT);
    float* LA = (float*)alloc(szLA);
    char*  R  = (char*)alloc(szR);
    __hip_bfloat16* A1  = (__hip_bfloat16*)R;
    __hip_bfloat16* W1  = (__hip_bfloat16*)(R + szA1);
    __hip_bfloat16* XBC = (__hip_bfloat16*)(R + szA1 + szW1);
    short* SS = (short*)R;
    __hip_bfloat16* Yb = (__hip_bfloat16*)R;
    float* Cpart = (float*)R;     // dead after gate_kernel (A1/W1/XBC/SS/Yb all consumed)

    short* Hp = (short*)alloc(szHp);
    float* CU = (float*)alloc(szCU);
    if (off > ws_size) return;   // clean fail instead of OOB crash

    // 1. fused converts: weights + x (A1 rows = b*SEQ+t, unflipped)
    int n1 = 2 * NPROJ * DMODEL / 4;
    int n2 = 2 * DMODEL * DINNER / 4;
    int n3 = 4096 * DMODEL / 4;
    cvt3_kernel<<<(n1 + n2 + n3 + 255) / 256, 256, 0, stream>>>(in_w, W1, n1, out_w, W2, n2, x, A1, n3);

    // 2. in_proj GEMM: 64x128 tiles, both dirs fused (z = dir), dir1 flips A rows in-gather
    {
        dim3 grid(4096 / 64, (NPROJ + 127) / 128, 2);
        gemm_bt<<<grid, 256, 0, stream>>>(A1, 0,
                                          W1, (size_t)NPROJ * DMODEL,
                                          nullptr, Z, XBC, DT, LA, dt_bias, A_log,
                                          4096, NPROJ, DMODEL, 1, 2, 1);
    }

    // 3. conv + silu
    conv_kernel<<<4 * 128, 256, 0, stream>>>(XBC, conv_w, conv_b, XH, BM, CM);

    // 4. SSD chunked scan (3-pass)
    ssd1_kernel<<<4 * NH * NCH, 256, 0, stream>>>(XH, BM, DT, LA, SS, CU);
    ssd2_kernel<<<4 * NH * 4, 256, 0, stream>>>(SS, CU, Hp);
    ssd3_kernel<<<4 * NH * NCH, 256, 0, stream>>>(XH, BM, CM, DT, CU, Hp, Yb);

    // 5. gating + RMSNorm (A2 == Z, in-place)
    gate_kernel<<<2 * 4096, 192, 0, stream>>>(Yb, XH, Z, Dp, norm_w, Z);

    // 6. out_proj: partials to workspace (plain stores, z = dir*2 + kslice), then reduce
    {
        dim3 grid(4096 / 64, DMODEL / 128, 4);
        gemm_bt<<<grid, 256, 0, stream>>>(Z, (size_t)4096 * DINNER,
                                          W2, (size_t)DMODEL * DINNER,
                                          Cpart, nullptr, nullptr, nullptr, nullptr, nullptr, nullptr,
                                          4096, DMODEL, DINNER, 2, 1, 0);
    }
    reduce4_kernel<<<4096 * 192 / 256, 256, 0, stream>>>(Cpart, out);
}

// Round 6
// 347.233 us; speedup vs baseline: 1.2587x; 1.0186x over previous
//
#include <hip/hip_runtime.h>
#include <hip/hip_bf16.h>

typedef __attribute__((ext_vector_type(8))) short short8;
typedef __attribute__((ext_vector_type(4))) short bfx4;
typedef __attribute__((ext_vector_type(4))) float floatx4;

#define SEQ     2048
#define DMODEL  768
#define DINNER  1536
#define DSTATE  128
#define NH      24
#define CONVDIM 1792
#define NPROJ   3352   // 2*DINNER + 2*DSTATE + NH
#define QCH     64     // SSD chunk length
#define NCH     (SEQ / QCH)   // 32 chunks

__device__ inline float bf2f(short s) {
    return __uint_as_float(((unsigned)(unsigned short)s) << 16);
}
__device__ inline short f2bf(float f) {
    __hip_bfloat16 h = __float2bfloat16(f);
    return *reinterpret_cast<short*>(&h);
}
__device__ inline void gl_lds16(const void* g, void* l) {
    __builtin_amdgcn_global_load_lds((const __attribute__((address_space(1))) unsigned int*)g,
                                     (__attribute__((address_space(3))) unsigned int*)l, 16, 0, 0);
}

// ---------------------------------------------------------------- fused converts (float4), 3 segments
__global__ __launch_bounds__(256) void cvt3_kernel(const float* __restrict__ s1, __hip_bfloat16* __restrict__ d1, int n1,
                                                   const float* __restrict__ s2, __hip_bfloat16* __restrict__ d2, int n2,
                                                   const float* __restrict__ s3, __hip_bfloat16* __restrict__ d3, int n3) {
    int i = blockIdx.x * 256 + threadIdx.x;
    const float* src; __hip_bfloat16* dst; int idx;
    if (i < n1)                { src = s1; dst = d1; idx = i; }
    else if (i < n1 + n2)      { src = s2; dst = d2; idx = i - n1; }
    else if (i < n1 + n2 + n3) { src = s3; dst = d3; idx = i - n1 - n2; }
    else return;
    float4 v = *(const float4*)(src + (size_t)idx * 4);
    bfx4 o = { f2bf(v.x), f2bf(v.y), f2bf(v.z), f2bf(v.w) };
    *(bfx4*)((short*)dst + (size_t)idx * 4) = o;
}

// ---------------------------------------------------------------- GEMM 64x128 tile, BK=32, 4 waves, double-buffered
// R5 win: coalesced epilogues broke the 540 GB/s fine-granule write wall (104->91us in_proj).
// R6 levers (both occupancy/traffic, K-loop byte-identical):
//  (1) Tr overlays dead As/Bs space -> LDS 33.3KB -> 24.6KB -> 6 blocks/CU (back to R4 residency,
//      now WITH the fast epilogue). Epilogue __syncthreads fences the overlay.
//  (2) mode 1 (out_proj): dir-sum fused INTO the gemm — z = kslice only; each block loops
//      dir0,dir1 internally (dir1 gathers flipped Z rows), one acc -> partials 4->2 slices
//      (50.3->25.2 MB), reduce2 has no flip.
// mode 2 (in_proj): z = dir; LDS-transpose epilogue, coalesced short8 stores; dt-head scalar.
__global__ __launch_bounds__(256) void gemm_bt(const __hip_bfloat16* __restrict__ Abase, size_t aStride,
                                               const __hip_bfloat16* __restrict__ Bbase, size_t bStride,
                                               float* __restrict__ C,
                                               __hip_bfloat16* __restrict__ Zb,
                                               __hip_bfloat16* __restrict__ Xb,
                                               float* __restrict__ DT,
                                               float* __restrict__ LA,
                                               const float* __restrict__ dtbias,
                                               const float* __restrict__ Alog,
                                               int M, int N, int K, int zdiv, int mode, int flipA) {
    __shared__ short As[2][32 * 64];   // 4 KB per buf: 32 lines x 128 B (rows l & l+32 packed)
    __shared__ short Bs[2][64 * 64];   // 8 KB per buf: 64 lines x 128 B (rows l & l+64 packed)
    int tid = threadIdx.x;
    int w = tid >> 6, lane = tid & 63;
    int q = lane >> 4, mm = lane & 15;
    int wm = w >> 1, wn = w & 1;       // wave tile 32x64 within 64x128 block tile
    int m0 = blockIdx.x * 64, n0 = blockIdx.y * 128;
    int z = blockIdx.z;
    // mode 1: z = kslice (zdiv slices); dirs looped internally.  mode 2: z = dir (zdiv == 1).
    int nd   = (mode == 1) ? 2 : 1;
    int dir0 = (mode == 1) ? 0 : z;
    int ks   = (mode == 1) ? z : 0;
    int kl   = K / zdiv;
    int kbeg = ks * kl;
    int niter = kl / 32;

    // staging geometry (dir-invariant parts)
    int aRow, aCh, aldso;
    {
        int ln = w * 8 + (lane >> 3);    // line 0..31
        int s  = lane & 7;               // slot within line
        int c  = s ^ (ln & 7);
        aRow = (c < 4) ? ln : ln + 32;   // row within 64-row tile
        aCh  = (c < 4) ? c : (c ^ 4);
        aldso = w * 1024;                // bytes
    }
    int bRow[2], bCh[2], bldso[2];
#pragma unroll
    for (int j = 0; j < 2; j++) {
        int widx = w * 2 + j;            // 0..7
        int ln = widx * 8 + (lane >> 3); // line 0..63
        int s  = lane & 7;
        int c  = s ^ (ln & 7);
        bRow[j] = (c < 4) ? ln : ln + 64;
        bCh[j]  = (c < 4) ? c : (c ^ 4);
        bldso[j] = widx * 1024;          // bytes
    }

    floatx4 acc[8];
#pragma unroll
    for (int i = 0; i < 8; i++) acc[i] = (floatx4){0.f, 0.f, 0.f, 0.f};

    int slotA = (q ^ (mm & 7) ^ (wm << 2)) * 8;   // elements
    int slotB = (q ^ (mm & 7) ^ (wn << 2)) * 8;

    for (int d = 0; d < nd; d++) {
        int dir = (mode == 1) ? d : dir0;
        int fA  = (mode == 1) ? d : (flipA && dir);   // mode1: dir1 gathers flipped rows
        const short* Ag = (const short*)Abase + (size_t)dir * aStride;
        const short* Bg = (const short*)Bbase + (size_t)dir * bStride;
        size_t aoff;
        {
            int ar = m0 + aRow;
            if (fA) { int bb = ar >> 11, tt = ar & 2047; ar = (bb << 11) + (2047 - tt); }
            aoff = (size_t)ar * K + aCh * 8;
        }
        size_t boff[2];
#pragma unroll
        for (int j = 0; j < 2; j++) {
            int br = n0 + bRow[j]; if (br > N - 1) br = N - 1;   // dup rows; cols skipped on store
            boff[j] = (size_t)br * K + bCh[j] * 8;
        }
        auto stage = [&](int buf, int k0) {
            gl_lds16(Ag + aoff + kbeg + k0, (char*)&As[buf][0] + aldso);
            gl_lds16(Bg + boff[0] + kbeg + k0, (char*)&Bs[buf][0] + bldso[0]);
            gl_lds16(Bg + boff[1] + kbeg + k0, (char*)&Bs[buf][0] + bldso[1]);
        };
        // inter-dir safety: buf0's last readers (it = niter-2) finished before it = niter-1's
        // entry barrier, which every thread has passed before issuing this stage.
        stage(0, 0);
        for (int it = 0; it < niter; it++) {
            __syncthreads();                           // drains vmcnt: buf[it&1] staged; prior reads done
            if (it + 1 < niter) stage((it + 1) & 1, (it + 1) * 32);
            const short* Ab = &As[it & 1][0];
            const short* Bb = &Bs[it & 1][0];
            short8 af[2], bfr[4];
#pragma unroll
            for (int mb = 0; mb < 2; mb++)
                af[mb] = *(const short8*)&Ab[(mb * 16 + mm) * 64 + slotA];
#pragma unroll
            for (int nb = 0; nb < 4; nb++)
                bfr[nb] = *(const short8*)&Bb[(nb * 16 + mm) * 64 + slotB];
#pragma unroll
            for (int mb = 0; mb < 2; mb++)
#pragma unroll
                for (int nb = 0; nb < 4; nb++)
                    acc[mb * 4 + nb] = __builtin_amdgcn_mfma_f32_16x16x32_bf16(af[mb], bfr[nb], acc[mb * 4 + nb], 0, 0, 0);
        }
    }

    if (mode == 1) {
        // out_proj: dir-summed partial -> slice z (plain fp32 stores, rows already in out order)
        float* Cz = C + (size_t)z * 4096 * 768;
#pragma unroll
        for (int mb = 0; mb < 2; mb++)
#pragma unroll
            for (int nb = 0; nb < 4; nb++) {
                int col = n0 + wn * 64 + nb * 16 + mm;
#pragma unroll
                for (int r = 0; r < 4; r++) {
                    int rr = m0 + wm * 32 + mb * 16 + q * 4 + r;
                    Cz[(size_t)rr * 768 + col] = acc[mb * 4 + nb][r];
                }
            }
        return;
    }

    int dir = dir0;
    __hip_bfloat16* Zb2 = Zb + (size_t)dir * 4096 * DINNER;
    __hip_bfloat16* Xb2 = Xb + (size_t)dir * 4096 * CONVDIM;

    if (n0 + 128 <= DINNER + CONVDIM) {
        // fast path: transpose + coalesced stores. Tr OVERLAYS Bs (dead after K-loop;
        // p-loop entry __syncthreads fences all prior ds_reads). 32*136 shorts <= 8192 of Bs.
        short (*Tr)[136] = (short (*)[136])&Bs[0][0];
        short* dstBase; int ldd, c0;
        if (n0 < DINNER) { dstBase = (short*)Zb2; ldd = DINNER; c0 = n0; }
        else             { dstBase = (short*)Xb2; ldd = CONVDIM; c0 = n0 - DINNER; }
#pragma unroll
        for (int p = 0; p < 2; p++) {
            __syncthreads();
            if (wm == p) {
#pragma unroll
                for (int mb = 0; mb < 2; mb++)
#pragma unroll
                    for (int nb = 0; nb < 4; nb++)
#pragma unroll
                        for (int r = 0; r < 4; r++)
                            Tr[mb * 16 + q * 4 + r][wn * 64 + nb * 16 + mm] =
                                f2bf(acc[mb * 4 + nb][r]);
            }
            __syncthreads();
            int row = tid >> 3, c16 = (tid & 7) * 16;
            short8 v0 = *(const short8*)&Tr[row][c16];
            short8 v1 = *(const short8*)&Tr[row][c16 + 8];
            short* dp = dstBase + (size_t)(m0 + p * 32 + row) * ldd + c0 + c16;
            *(short8*)dp = v0;
            *(short8*)(dp + 8) = v1;
        }
        return;
    }

    // dt-head block (n0 == DINNER+CONVDIM): scalar path with softplus
    float* DT2 = DT + (size_t)dir * 4096 * NH;
    float* LA2 = LA + (size_t)dir * 4096 * NH;
    const float* dtb2 = dtbias + dir * NH;
    const float* Al2  = Alog + dir * NH;
#pragma unroll
    for (int mb = 0; mb < 2; mb++) {
#pragma unroll
        for (int nb = 0; nb < 4; nb++) {
            int col = n0 + wn * 64 + nb * 16 + mm;
            if (col >= N) continue;
#pragma unroll
            for (int r = 0; r < 4; r++) {
                int rr = m0 + wm * 32 + mb * 16 + q * 4 + r;
                float v = acc[mb * 4 + nb][r];
                int hh = col - (DINNER + CONVDIM);
                float raw = v + dtb2[hh];
                float dtv = (raw > 20.f) ? raw : log1pf(__expf(raw));
                float Av  = -__expf(Al2[hh]);
                DT2[(size_t)rr * NH + hh] = dtv;
                LA2[(size_t)rr * NH + hh] = dtv * Av;
            }
        }
    }
}

// ---------------------------------------------------------------- out_proj reduce: out = P0 + P1 (dirs pre-summed)
__global__ __launch_bounds__(256) void reduce2_kernel(const float* __restrict__ P, float* __restrict__ out) {
    int idx = blockIdx.x * 256 + threadIdx.x;   // 4096*192 float4 slots
    const size_t sl = (size_t)4096 * 192;
    const float4* P4 = (const float4*)P;
    float4 a = P4[idx];
    float4 b = P4[sl + idx];
    float4 o = { a.x + b.x, a.y + b.y, a.z + b.z, a.w + b.w };
    ((float4*)out)[idx] = o;
}

// ---------------------------------------------------------------- conv (depthwise K=4) + silu
__global__ __launch_bounds__(256) void conv_kernel(const __hip_bfloat16* __restrict__ Xb,
                                                   const float* __restrict__ conv_w,
                                                   const float* __restrict__ conv_b,
                                                   __hip_bfloat16* __restrict__ xh,
                                                   __hip_bfloat16* __restrict__ Bm,
                                                   __hip_bfloat16* __restrict__ Cm) {
    int db  = blockIdx.x >> 7;
    int dir = db >> 1;
    int t0  = (blockIdx.x & 127) * 16;
    int c8  = threadIdx.x * 8;
    if (c8 >= CONVDIM) return;

    float wk[4][8], bs[8];
#pragma unroll
    for (int j = 0; j < 8; j++) {
        bs[j] = conv_b[dir * CONVDIM + c8 + j];
#pragma unroll
        for (int k = 0; k < 4; k++) wk[k][j] = conv_w[((size_t)dir * CONVDIM + c8 + j) * 4 + k];
    }

    const short* xrow = (const short*)Xb + (size_t)db * SEQ * CONVDIM + c8;
    short8 win[4];
    const short8 zer = {0, 0, 0, 0, 0, 0, 0, 0};
#pragma unroll
    for (int k = 0; k < 3; k++) {
        int ts = t0 - 3 + k;
        win[k] = (ts >= 0) ? *(const short8*)(xrow + (size_t)ts * CONVDIM) : zer;
    }

    for (int tt = 0; tt < 16; tt++) {
        int t = t0 + tt;
        win[3] = *(const short8*)(xrow + (size_t)t * CONVDIM);
        short8 outv;
#pragma unroll
        for (int j = 0; j < 8; j++) {
            float acc = bs[j];
#pragma unroll
            for (int k = 0; k < 4; k++) acc += wk[k][j] * bf2f(win[k][j]);
            float sv = acc / (1.f + __expf(-acc));
            outv[j] = f2bf(sv);
        }
        if (c8 < DINNER)
            *(short8*)((short*)xh + (size_t)(db * SEQ + t) * DINNER + c8) = outv;
        else if (c8 < DINNER + DSTATE)
            *(short8*)((short*)Bm + (size_t)(db * SEQ + t) * DSTATE + (c8 - DINNER)) = outv;
        else
            *(short8*)((short*)Cm + (size_t)(db * SEQ + t) * DSTATE + (c8 - DINNER - DSTATE)) = outv;
        win[0] = win[1]; win[1] = win[2]; win[2] = win[3];
    }
}

// ---------------------------------------------------------------- SSD pass 1
__global__ __launch_bounds__(256) void ssd1_kernel(const __hip_bfloat16* __restrict__ XH,
                                                   const __hip_bfloat16* __restrict__ BMh,
                                                   const float* __restrict__ DT,
                                                   const float* __restrict__ LA,
                                                   short* __restrict__ SS,
                                                   float* __restrict__ CUM) {
    int blk = blockIdx.x;
    int ck = blk & 31;
    int dbh = blk >> 5;
    int hh = dbh % NH, db = dbh / NH;
    int base_row = db * SEQ + ck * QCH;

    __shared__ float cum_s[QCH], dt_s[QCH];
    __shared__ short Xt[64][72];
    __shared__ short Bt[128][72];

    int tid = threadIdx.x;
    int lane = tid & 63, w = tid >> 6;
    int q = lane >> 4, mm = lane & 15;

    if (tid < QCH) {
        float la  = LA[(size_t)(base_row + tid) * NH + hh];
        float dtv = DT[(size_t)(base_row + tid) * NH + hh];
        float cs = la;
#pragma unroll
        for (int d = 1; d < 64; d <<= 1) {
            float u = __shfl_up(cs, d);
            if (tid >= d) cs += u;
        }
        cum_s[tid] = cs;
        dt_s[tid] = dtv;
        CUM[(size_t)dbh * SEQ + ck * QCH + tid] = cs;
    }
    __syncthreads();
    float cumL = cum_s[QCH - 1];

    {
        int s2 = (tid & 31) * 2, pb = tid >> 5;
        float f0 = dt_s[s2]     * __expf(cumL - cum_s[s2]);
        float f1 = dt_s[s2 + 1] * __expf(cumL - cum_s[s2 + 1]);
        const short* r0 = (const short*)XH + (size_t)(base_row + s2) * DINNER + hh * 64 + pb * 8;
        const short* r1 = r0 + DINNER;
        short8 x0 = *(const short8*)r0;
        short8 x1 = *(const short8*)r1;
#pragma unroll
        for (int j = 0; j < 8; j++) {
            unsigned lo = (unsigned short)f2bf(f0 * bf2f(x0[j]));
            unsigned hi = (unsigned short)f2bf(f1 * bf2f(x1[j]));
            *(unsigned*)&Xt[pb * 8 + j][s2] = lo | (hi << 16);
        }
    }
    {
        int s2 = (tid & 31) * 2, nb = tid >> 5;
        const short* r0 = (const short*)BMh + (size_t)(base_row + s2) * DSTATE + nb * 16;
        const short* r1 = r0 + DSTATE;
        short8 b0a = *(const short8*)r0,  b0b = *(const short8*)(r0 + 8);
        short8 b1a = *(const short8*)r1,  b1b = *(const short8*)(r1 + 8);
#pragma unroll
        for (int j = 0; j < 8; j++) {
            *(unsigned*)&Bt[nb * 16 + j][s2] =
                (unsigned)(unsigned short)b0a[j] | ((unsigned)(unsigned short)b1a[j] << 16);
            *(unsigned*)&Bt[nb * 16 + 8 + j][s2] =
                (unsigned)(unsigned short)b0b[j] | ((unsigned)(unsigned short)b1b[j] << 16);
        }
    }
    __syncthreads();

    floatx4 acc[8];
#pragma unroll
    for (int i = 0; i < 8; i++) acc[i] = (floatx4){0.f, 0.f, 0.f, 0.f};
#pragma unroll
    for (int kk = 0; kk < 2; kk++) {
        short8 a = *(const short8*)&Xt[w * 16 + mm][kk * 32 + q * 8];
#pragma unroll
        for (int cb = 0; cb < 8; cb++) {
            short8 b = *(const short8*)&Bt[cb * 16 + mm][kk * 32 + q * 8];
            acc[cb] = __builtin_amdgcn_mfma_f32_16x16x32_bf16(a, b, acc[cb], 0, 0, 0);
        }
    }
    short* Sp = SS + (size_t)blk * 8192;
#pragma unroll
    for (int cb = 0; cb < 8; cb++)
#pragma unroll
        for (int r = 0; r < 4; r++)
            Sp[(w * 16 + q * 4 + r) * DSTATE + cb * 16 + mm] = f2bf(acc[cb][r]);
}

// ---------------------------------------------------------------- SSD pass 2: inter-chunk scan
__global__ __launch_bounds__(256) void ssd2_kernel(const short* __restrict__ SS,
                                                   const float* __restrict__ CUM,
                                                   short* __restrict__ Hprev) {
    int blk = blockIdx.x;
    int dbh = blk >> 2, part = blk & 3;
    int off = part * 2048 + threadIdx.x * 8;
    size_t base = (size_t)dbh * NCH * 8192 + off;
    float h[8];
#pragma unroll
    for (int j = 0; j < 8; j++) h[j] = 0.f;
    for (int c = 0; c < NCH; c++) {
        float W = __expf(CUM[(size_t)dbh * SEQ + c * QCH + QCH - 1]);
        size_t p = base + (size_t)c * 8192;
        short8 s = *(const short8*)(SS + p);
        short8 o;
#pragma unroll
        for (int j = 0; j < 8; j++) o[j] = f2bf(h[j]);
        *(short8*)(Hprev + p) = o;
#pragma unroll
        for (int j = 0; j < 8; j++) h[j] = fmaf(h[j], W, bf2f(s[j]));
    }
}

// ---------------------------------------------------------------- SSD pass 3
__global__ __launch_bounds__(256) void ssd3_kernel(const __hip_bfloat16* __restrict__ XH,
                                                   const __hip_bfloat16* __restrict__ BMh,
                                                   const __hip_bfloat16* __restrict__ CMh,
                                                   const float* __restrict__ DT,
                                                   const float* __restrict__ CUM,
                                                   const short* __restrict__ Hprev,
                                                   __hip_bfloat16* __restrict__ Yb) {
    int blk = blockIdx.x;
    int ck = blk & 31;
    int dbh = blk >> 5;
    int hh = dbh % NH, db = dbh / NH;
    int base_row = db * SEQ + ck * QCH;

    __shared__ float cum_s[QCH], dt_s[QCH];
    __shared__ short Ct[64][136];
    __shared__ short G[64][72];
    __shared__ short Xt[64][72];

    int tid = threadIdx.x;
    int lane = tid & 63, w = tid >> 6;
    int q = lane >> 4, mm = lane & 15;

    if (tid < QCH) {
        cum_s[tid] = CUM[(size_t)dbh * SEQ + ck * QCH + tid];
        dt_s[tid]  = DT[(size_t)(base_row + tid) * NH + hh];
    }

    const short* Cg = (const short*)CMh + (size_t)base_row * DSTATE;
    const short* Bg = (const short*)BMh + (size_t)base_row * DSTATE;
    floatx4 P[4];
#pragma unroll
    for (int i = 0; i < 4; i++) P[i] = (floatx4){0.f, 0.f, 0.f, 0.f};
#pragma unroll
    for (int kk = 0; kk < 4; kk++) {
        short8 a = *(const short8*)(Cg + (size_t)(w * 16 + mm) * DSTATE + kk * 32 + q * 8);
#pragma unroll
        for (int cb = 0; cb < 4; cb++) {
            short8 b = *(const short8*)(Bg + (size_t)(cb * 16 + mm) * DSTATE + kk * 32 + q * 8);
            P[cb] = __builtin_amdgcn_mfma_f32_16x16x32_bf16(a, b, P[cb], 0, 0, 0);
        }
    }
    __syncthreads();

    {
        int t = tid & 63, nb4 = tid >> 6;
        float wt = __expf(cum_s[t]);
        const short* src = Cg + (size_t)t * DSTATE + nb4 * 32;
#pragma unroll
        for (int u = 0; u < 2; u++) {
            short8 v = *(const short8*)(src + u * 16);
            short8 v2 = *(const short8*)(src + u * 16 + 8);
#pragma unroll
            for (int j = 0; j < 4; j++) {
                unsigned lo = (unsigned short)f2bf(wt * bf2f(v[2 * j]));
                unsigned hi = (unsigned short)f2bf(wt * bf2f(v[2 * j + 1]));
                *(unsigned*)&Ct[t][nb4 * 32 + u * 16 + 2 * j] = lo | (hi << 16);
                lo = (unsigned short)f2bf(wt * bf2f(v2[2 * j]));
                hi = (unsigned short)f2bf(wt * bf2f(v2[2 * j + 1]));
                *(unsigned*)&Ct[t][nb4 * 32 + u * 16 + 8 + 2 * j] = lo | (hi << 16);
            }
        }
    }
    {
        int s2 = (tid & 31) * 2, pb = tid >> 5;
        const short* r0 = (const short*)XH + (size_t)(base_row + s2) * DINNER + hh * 64 + pb * 8;
        const short* r1 = r0 + DINNER;
        short8 x0 = *(const short8*)r0;
        short8 x1 = *(const short8*)r1;
#pragma unroll
        for (int j = 0; j < 8; j++) {
            *(unsigned*)&Xt[pb * 8 + j][s2] =
                (unsigned)(unsigned short)x0[j] | ((unsigned)(unsigned short)x1[j] << 16);
        }
    }
#pragma unroll
    for (int cb = 0; cb < 4; cb++) {
#pragma unroll
        for (int r = 0; r < 4; r++) {
            int t = w * 16 + q * 4 + r;
            int s = cb * 16 + mm;
            float g = (s <= t) ? P[cb][r] * __expf(cum_s[t] - cum_s[s]) * dt_s[s] : 0.f;
            G[t][s] = f2bf(g);
        }
    }
    __syncthreads();

    floatx4 Y[4];
#pragma unroll
    for (int i = 0; i < 4; i++) Y[i] = (floatx4){0.f, 0.f, 0.f, 0.f};
#pragma unroll
    for (int kk = 0; kk < 2; kk++) {
        short8 a = *(const short8*)&G[w * 16 + mm][kk * 32 + q * 8];
#pragma unroll
        for (int cb = 0; cb < 4; cb++) {
            short8 b = *(const short8*)&Xt[cb * 16 + mm][kk * 32 + q * 8];
            Y[cb] = __builtin_amdgcn_mfma_f32_16x16x32_bf16(a, b, Y[cb], 0, 0, 0);
        }
    }
    const short* Hc = Hprev + (size_t)blk * 8192;
#pragma unroll
    for (int kk = 0; kk < 4; kk++) {
        short8 a = *(const short8*)&Ct[w * 16 + mm][kk * 32 + q * 8];
#pragma unroll
        for (int cb = 0; cb < 4; cb++) {
            short8 b = *(const short8*)(Hc + (size_t)(cb * 16 + mm) * DSTATE + kk * 32 + q * 8);
            Y[cb] = __builtin_amdgcn_mfma_f32_16x16x32_bf16(a, b, Y[cb], 0, 0, 0);
        }
    }
#pragma unroll
    for (int cb = 0; cb < 4; cb++)
#pragma unroll
        for (int r = 0; r < 4; r++)
            Yb[(size_t)(base_row + w * 16 + q * 4 + r) * DINNER + hh * 64 + cb * 16 + mm] =
                __float2bfloat16(Y[cb][r]);
}

// ---------------------------------------------------------------- gating + RMSNorm (192 thr x 8 ch)
__global__ __launch_bounds__(192) void gate_kernel(const __hip_bfloat16* __restrict__ Yb,
                                                   const __hip_bfloat16* __restrict__ xh,
                                                   const __hip_bfloat16* __restrict__ Zb,
                                                   const float* __restrict__ Dp,
                                                   const float* __restrict__ norm_w,
                                                   __hip_bfloat16* __restrict__ A2) {
    int row = blockIdx.x;
    int dir = row >> 12;
    int c8 = threadIdx.x * 8;
    int hd = c8 >> 6;
    const short* yr = (const short*)Yb + (size_t)row * DINNER + c8;
    const short* xr = (const short*)xh + (size_t)row * DINNER + c8;
    const short* zr = (const short*)Zb + (size_t)row * DINNER + c8;

    short8 y8 = *(const short8*)yr;
    short8 x8 = *(const short8*)xr;
    short8 z8 = *(const short8*)zr;
    float Dv = Dp[dir * NH + hd];

    float vals[8];
    float ss = 0.f;
#pragma unroll
    for (int j = 0; j < 8; j++) {
        float v = bf2f(y8[j]) + Dv * bf2f(x8[j]);
        float z = bf2f(z8[j]);
        v *= z / (1.f + __expf(-z));
        vals[j] = v;
        ss += v * v;
    }
#pragma unroll
    for (int off = 32; off; off >>= 1) ss += __shfl_down(ss, off);
    __shared__ float ls[3];
    if ((threadIdx.x & 63) == 0) ls[threadIdx.x >> 6] = ss;
    __syncthreads();
    float tot = ls[0] + ls[1] + ls[2];
    float scale = rsqrtf(tot / (float)DINNER + 1e-5f);

    const float* nw = norm_w + dir * DINNER + c8;
    short8 o;
#pragma unroll
    for (int j = 0; j < 8; j++) o[j] = f2bf(vals[j] * scale * nw[j]);
    *(short8*)((short*)A2 + (size_t)row * DINNER + c8) = o;
}

// ---------------------------------------------------------------- launch
extern "C" void kernel_launch(void* const* d_in, const int* in_sizes, int n_in,
                              void* d_out, int out_size, void* d_ws, size_t ws_size,
                              hipStream_t stream) {
    const float* x        = (const float*)d_in[0];
    const float* in_w     = (const float*)d_in[1];
    const float* conv_w   = (const float*)d_in[2];
    const float* conv_b   = (const float*)d_in[3];
    const float* dt_bias  = (const float*)d_in[4];
    const float* A_log    = (const float*)d_in[5];
    const float* Dp       = (const float*)d_in[6];
    const float* norm_w   = (const float*)d_in[7];
    const float* out_w    = (const float*)d_in[8];
    float* out = (float*)d_out;

    const size_t szW2 = (size_t)2 * DMODEL * DINNER * 2;
    const size_t szZ  = (size_t)8192 * DINNER * 2;
    const size_t szXH = (size_t)8192 * DINNER * 2;
    const size_t szBM = (size_t)8192 * DSTATE * 2;
    const size_t szCM = szBM;
    const size_t szDT = (size_t)8192 * NH * 4;
    const size_t szLA = szDT;
    const size_t szA1 = (size_t)4096 * DMODEL * 2;     // unflipped, shared by both dirs
    const size_t szW1 = (size_t)2 * NPROJ * DMODEL * 2;
    const size_t szXB = (size_t)8192 * CONVDIM * 2;
    const size_t szYb = (size_t)8192 * DINNER * 2;
    const size_t szSS = (size_t)96 * NCH * 8192 * 2;   // 50.33 MB
    const size_t szCp = (size_t)2 * 4096 * 768 * 4;    // 25.2 MB (2 dir-summed K-slices)
    const size_t szRa = szA1 + szW1 + szXB;
    size_t szR = szRa;
    if (szR < szYb) szR = szYb;
    if (szR < szSS) szR = szSS;
    if (szR < szCp) szR = szCp;
    const size_t szHp = szSS;
    const size_t szCU = (size_t)96 * SEQ * 4;

    char* ws = (char*)d_ws;
    size_t off = 0;
    auto alloc = [&](size_t bytes) { char* p = ws + off; off += (bytes + 255) & ~(size_t)255; return p; };

    __hip_bfloat16* W2 = (__hip_bfloat16*)alloc(szW2);
    __hip_bfloat16* Z  = (__hip_bfloat16*)alloc(szZ);
    __hip_bfloat16* XH = (__hip_bfloat16*)alloc(szXH);
    __hip_bfloat16* BM = (__hip_bfloat16*)alloc(szBM);
    __hip_bfloat16* CM = (__hip_bfloat16*)alloc(szCM);
    float* DT = (float*)alloc(szDT);
    float* LA = (float*)alloc(szLA);
    char*  R  = (char*)alloc(szR);
    __hip_bfloat16* A1  = (__hip_bfloat16*)R;
    __hip_bfloat16* W1  = (__hip_bfloat16*)(R + szA1);
    __hip_bfloat16* XBC = (__hip_bfloat16*)(R + szA1 + szW1);
    short* SS = (short*)R;
    __hip_bfloat16* Yb = (__hip_bfloat16*)R;
    float* Cpart = (float*)R;     // dead after gate_kernel (A1/W1/XBC/SS/Yb all consumed)

    short* Hp = (short*)alloc(szHp);
    float* CU = (float*)alloc(szCU);
    if (off > ws_size) return;   // clean fail instead of OOB crash

    // 1. fused converts: weights + x (A1 rows = b*SEQ+t, unflipped)
    int n1 = 2 * NPROJ * DMODEL / 4;
    int n2 = 2 * DMODEL * DINNER / 4;
    int n3 = 4096 * DMODEL / 4;
    cvt3_kernel<<<(n1 + n2 + n3 + 255) / 256, 256, 0, stream>>>(in_w, W1, n1, out_w, W2, n2, x, A1, n3);

    // 2. in_proj GEMM: 64x128 tiles, both dirs fused (z = dir), dir1 flips A rows in-gather
    {
        dim3 grid(4096 / 64, (NPROJ + 127) / 128, 2);
        gemm_bt<<<grid, 256, 0, stream>>>(A1, 0,
                                          W1, (size_t)NPROJ * DMODEL,
                                          nullptr, Z, XBC, DT, LA, dt_bias, A_log,
                                          4096, NPROJ, DMODEL, 1, 2, 1);
    }

    // 3. conv + silu
    conv_kernel<<<4 * 128, 256, 0, stream>>>(XBC, conv_w, conv_b, XH, BM, CM);

    // 4. SSD chunked scan (3-pass)
    ssd1_kernel<<<4 * NH * NCH, 256, 0, stream>>>(XH, BM, DT, LA, SS, CU);
    ssd2_kernel<<<4 * NH * 4, 256, 0, stream>>>(SS, CU, Hp);
    ssd3_kernel<<<4 * NH * NCH, 256, 0, stream>>>(XH, BM, CM, DT, CU, Hp, Yb);

    // 5. gating + RMSNorm (A2 == Z, in-place)
    gate_kernel<<<2 * 4096, 192, 0, stream>>>(Yb, XH, Z, Dp, norm_w, Z);

    // 6. out_proj: z = kslice (2), dirs fused in-kernel (dir1 gathers flipped Z rows), then reduce2
    {
        dim3 grid(4096 / 64, DMODEL / 128, 2);
        gemm_bt<<<grid, 256, 0, stream>>>(Z, (size_t)4096 * DINNER,
                                          W2, (size_t)DMODEL * DINNER,
                                          Cpart, nullptr, nullptr, nullptr, nullptr, nullptr, nullptr,
                                          4096, DMODEL, DINNER, 2, 1, 0);
    }
    reduce2_kernel<<<4096 * 192 / 256, 256, 0, stream>>>(Cpart, out);
}